// Round 14
// baseline (885.948 us; speedup 1.0000x reference)
//
#include <hip/hip_runtime.h>
#include <hip/hip_bf16.h>
#include <math.h>

#define NNODES 50000
#define NEDGES 640000
#define NGRAPH 256
#define CIN 32
#define HD 128
#define NLAYER 5
#define LHID 64
#define COUT 10
#define EPS_GEN 1e-7f
#define INVN (1.f / (float)NNODES)
#define SCAN_BLOCKS 196

typedef __attribute__((ext_vector_type(8))) short short8;
typedef __attribute__((ext_vector_type(4))) float floatx4;

// truncating compensated split: v ~= bf(hi) + bf(lo); hi-truncation error is
// captured exactly by lo (subtraction exact); dropped residual ~2^-17 |v|.
__device__ __forceinline__ void fsplit(float v, short &hi, short &lo) {
    union { float f; unsigned u; } a; a.f = v;
    hi = (short)(a.u >> 16);
    union { unsigned u; float f; } b; b.u = a.u & 0xFFFF0000u;
    union { float f; unsigned u; } c; c.f = v - b.f;
    lo = (short)(c.u >> 16);
}

// ---------------- CSR build ----------------
__global__ void hist_kernel(const int* __restrict__ dst, int* __restrict__ deg, int e) {
    int i = blockIdx.x * blockDim.x + threadIdx.x;
    if (i < e) atomicAdd(&deg[dst[i]], 1);
}

__global__ void blocksum_kernel(const int* __restrict__ deg, int* __restrict__ bsum) {
    int i = blockIdx.x * 256 + threadIdx.x;
    int v = (i < NNODES) ? deg[i] : 0;
#pragma unroll
    for (int d = 32; d; d >>= 1) v += __shfl_down(v, d);
    __shared__ int ws4[4];
    if ((threadIdx.x & 63) == 0) ws4[threadIdx.x >> 6] = v;
    __syncthreads();
    if (threadIdx.x == 0) bsum[blockIdx.x] = ws4[0] + ws4[1] + ws4[2] + ws4[3];
}

__global__ void scanpartials_kernel(const int* __restrict__ bsum, int* __restrict__ bpre) {
    __shared__ int t[256];
    int i = threadIdx.x;
    t[i] = (i < SCAN_BLOCKS) ? bsum[i] : 0;
    __syncthreads();
    for (int d = 1; d < 256; d <<= 1) {
        int v = (i >= d) ? t[i - d] : 0;
        __syncthreads();
        t[i] += v;
        __syncthreads();
    }
    bpre[i] = (i == 0) ? 0 : t[i - 1];
}

__global__ void writeoff_kernel(const int* __restrict__ deg, const int* __restrict__ bpre,
                                int* __restrict__ off, int* __restrict__ cursor) {
    __shared__ int t[256];
    int tid = threadIdx.x;
    int i = blockIdx.x * 256 + tid;
    int v = (i < NNODES) ? deg[i] : 0;
    t[tid] = v;
    __syncthreads();
    for (int d = 1; d < 256; d <<= 1) {
        int u = (tid >= d) ? t[tid - d] : 0;
        __syncthreads();
        t[tid] += u;
        __syncthreads();
    }
    int excl = bpre[blockIdx.x] + t[tid] - v;
    if (i < NNODES) { off[i] = excl; cursor[i] = excl; }
    if (i == NNODES - 1) off[NNODES] = excl + v;
}

__global__ void scatter_kernel(const int* __restrict__ src, const int* __restrict__ dst,
                               const int* __restrict__ eattr, int* __restrict__ cursor,
                               int* __restrict__ pedge, int e) {
    int i = blockIdx.x * blockDim.x + threadIdx.x;
    if (i < e) {
        int slot = atomicAdd(&cursor[dst[i]], 1);
        pedge[slot] = src[i] | (eattr[i] << 27);
    }
}

// ---------------- weight split (once per launch) ----------------
__global__ void wsplit_kernel(const float* __restrict__ w1, const float* __restrict__ w2,
                              short* __restrict__ w1h, short* __restrict__ w1l,
                              short* __restrict__ w2h, short* __restrict__ w2l) {
    int i = blockIdx.x * 256 + threadIdx.x;
    if (i < NLAYER * 2 * HD * HD) {
        short hi, lo;
        fsplit(w1[i], hi, lo);
        w1h[i] = hi; w1l[i] = lo;
        fsplit(w2[i], hi, lo);
        w2h[i] = hi; w2l[i] = lo;
    }
}

// ---------------- input FC ----------------
__global__ __launch_bounds__(256) void fc_kernel(
    const float* __restrict__ x, const float* __restrict__ ncc,
    const float* __restrict__ w, const float* __restrict__ b,
    float* __restrict__ h) {
    __shared__ float ws[HD][41];
    __shared__ float bs[HD];
    int tid = threadIdx.x;
    for (int i = tid; i < HD * 40; i += 256) ws[i / 40][i % 40] = w[i];
    if (tid < HD) bs[tid] = b[tid];
    __syncthreads();
    int c = tid & 127;
    int hi = tid >> 7;
#pragma unroll
    for (int nn = 0; nn < 4; ++nn) {
        int node = blockIdx.x * 8 + nn * 2 + hi;
        const float4* xr = reinterpret_cast<const float4*>(x + (size_t)node * CIN);
        const float4* nr = reinterpret_cast<const float4*>(ncc + (size_t)node * 8);
        float acc = bs[c];
#pragma unroll
        for (int k4 = 0; k4 < 8; ++k4) {
            float4 xv = xr[k4];
            acc += xv.x * ws[c][k4 * 4 + 0];
            acc += xv.y * ws[c][k4 * 4 + 1];
            acc += xv.z * ws[c][k4 * 4 + 2];
            acc += xv.w * ws[c][k4 * 4 + 3];
        }
#pragma unroll
        for (int k4 = 0; k4 < 2; ++k4) {
            float4 nv = nr[k4];
            acc += nv.x * ws[c][32 + k4 * 4 + 0];
            acc += nv.y * ws[c][32 + k4 * 4 + 1];
            acc += nv.z * ws[c][32 + k4 * 4 + 2];
            acc += nv.w * ws[c][32 + k4 * 4 + 3];
        }
        h[(size_t)node * HD + c] = acc;
    }
}

// ---------------- softmax aggregation (fp32 gather) -> bf16 hi/lo split x0 ----------------
template <bool BN>
__global__ __launch_bounds__(256) void agg_kernel(
    const float* __restrict__ h, const int* __restrict__ off,
    const int* __restrict__ pedge, const float* __restrict__ edge_emb,
    const float* __restrict__ sums, const float* __restrict__ sqs,
    const float* __restrict__ g, const float* __restrict__ bb,
    short* __restrict__ x0h, short* __restrict__ x0l) {
    __shared__ float ee[4 * HD];
    __shared__ float scs[HD], shs[HD];
    int tid = threadIdx.x;
    ee[tid] = edge_emb[tid];
    ee[tid + 256] = edge_emb[tid + 256];
    if (BN && tid < HD) {
        float mu = sums[tid] * INVN;
        float var = fmaxf(sqs[tid] * INVN - mu * mu, 0.f);
        float is = rsqrtf(var + 1e-5f);
        float sc = g[tid] * is;
        scs[tid] = sc;
        shs[tid] = bb[tid] - mu * sc;
    }
    __syncthreads();

    int node = blockIdx.x * 4 + (tid >> 6);
    int lane = tid & 63;
    int half = lane >> 5;
    int c4 = (lane & 31) * 4;

    int b = off[node], e = off[node + 1];
    float4 sc4 = make_float4(1.f, 1.f, 1.f, 1.f);
    float4 sh4 = make_float4(0.f, 0.f, 0.f, 0.f);
    if (BN) {
        sc4 = *reinterpret_cast<const float4*>(&scs[c4]);
        sh4 = *reinterpret_cast<const float4*>(&shs[c4]);
    }
    float4 S = make_float4(0.f, 0.f, 0.f, 0.f);
    float4 T = make_float4(0.f, 0.f, 0.f, 0.f);
    int j = b + half;
    unsigned pnext = (j < e) ? (unsigned)pedge[j] : 0u;
    for (; j < e; j += 2) {
        unsigned p = pnext;
        if (j + 2 < e) pnext = (unsigned)pedge[j + 2];
        int s = p & 0x07FFFFFFu;
        int a = p >> 27;
        float4 v = *reinterpret_cast<const float4*>(&h[(size_t)s * HD + c4]);
        float4 ev = *reinterpret_cast<const float4*>(&ee[a * HD + c4]);
        if (BN) {
            v.x = fmaxf(fmaf(v.x, sc4.x, sh4.x), 0.f);
            v.y = fmaxf(fmaf(v.y, sc4.y, sh4.y), 0.f);
            v.z = fmaxf(fmaf(v.z, sc4.z, sh4.z), 0.f);
            v.w = fmaxf(fmaf(v.w, sc4.w, sh4.w), 0.f);
        }
        float m0 = fmaxf(v.x + ev.x, 0.f) + EPS_GEN;
        float m1 = fmaxf(v.y + ev.y, 0.f) + EPS_GEN;
        float m2 = fmaxf(v.z + ev.z, 0.f) + EPS_GEN;
        float m3 = fmaxf(v.w + ev.w, 0.f) + EPS_GEN;
        float e0 = __expf(m0), e1 = __expf(m1), e2 = __expf(m2), e3 = __expf(m3);
        S.x += e0; S.y += e1; S.z += e2; S.w += e3;
        T.x = fmaf(e0, m0, T.x); T.y = fmaf(e1, m1, T.y);
        T.z = fmaf(e2, m2, T.z); T.w = fmaf(e3, m3, T.w);
    }
    S.x += __shfl(S.x, lane ^ 32); S.y += __shfl(S.y, lane ^ 32);
    S.z += __shfl(S.z, lane ^ 32); S.w += __shfl(S.w, lane ^ 32);
    T.x += __shfl(T.x, lane ^ 32); T.y += __shfl(T.y, lane ^ 32);
    T.z += __shfl(T.z, lane ^ 32); T.w += __shfl(T.w, lane ^ 32);
    if (half == 0) {
        float4 r = *reinterpret_cast<const float4*>(&h[(size_t)node * HD + c4]);
        if (BN) {
            r.x = fmaxf(fmaf(r.x, sc4.x, sh4.x), 0.f);
            r.y = fmaxf(fmaf(r.y, sc4.y, sh4.y), 0.f);
            r.z = fmaxf(fmaf(r.z, sc4.z, sh4.z), 0.f);
            r.w = fmaxf(fmaf(r.w, sc4.w, sh4.w), 0.f);
        }
        if (e > b) {
            r.x += T.x / S.x; r.y += T.y / S.y;
            r.z += T.z / S.z; r.w += T.w / S.w;
        }
        float vv[4] = {r.x, r.y, r.z, r.w};
        short4 hv, lv;
        short hh4[4], ll4[4];
#pragma unroll
        for (int q = 0; q < 4; ++q) fsplit(vv[q], hh4[q], ll4[q]);
        hv.x = hh4[0]; hv.y = hh4[1]; hv.z = hh4[2]; hv.w = hh4[3];
        lv.x = ll4[0]; lv.y = ll4[1]; lv.z = ll4[2]; lv.w = ll4[3];
        *reinterpret_cast<short4*>(&x0h[(size_t)node * HD + c4]) = hv;
        *reinterpret_cast<short4*>(&x0l[(size_t)node * HD + c4]) = lv;
    }
}

// ---------------- MFMA GEMM: B-stationary LDS, barrier-free compute, 512 thr / BM=256 ----------------
template <int NPANEL, int KT, int NFULL, bool TRANS>
__global__ __launch_bounds__(512) void gemm_kernel(
    const short* __restrict__ Ahg, const short* __restrict__ Alg,
    const float* __restrict__ Afp,
    const short* __restrict__ Bhg, const short* __restrict__ Blg,
    const float* __restrict__ bias,
    const float* __restrict__ sums_in, const float* __restrict__ sqs_in,
    const float* __restrict__ g_in, const float* __restrict__ b_in,
    float* __restrict__ C, float* __restrict__ sums, float* __restrict__ sqs,
    int M) {
    constexpr int K = KT * 32;
    constexpr int BSTRIDE = K + 8;
    constexpr int NT = NPANEL / 16;
    __shared__ short Bs[2][NPANEL][BSTRIDE];
    __shared__ float scol[NPANEL], sqcol[NPANEL];
    __shared__ float sL[256], shL[256];
    int tid = threadIdx.x;
    int m0 = blockIdx.x * 256;
    int n0 = blockIdx.y * NPANEL;
    if (tid < NPANEL) { scol[tid] = 0.f; sqcol[tid] = 0.f; }
    if (TRANS && tid < K) {
        float mu = sums_in[tid] * INVN;
        float var = fmaxf(sqs_in[tid] * INVN - mu * mu, 0.f);
        float is = rsqrtf(var + 1e-5f);
        float sc = g_in[tid] * is;
        sL[tid] = sc;
        shL[tid] = b_in[tid] - mu * sc;
    }
    constexpr int ELEMS = NPANEL * (K / 8);
#pragma unroll
    for (int i = tid; i < ELEMS; i += 512) {
        int n = i / (K / 8);
        int k8 = (i % (K / 8)) * 8;
        *reinterpret_cast<short8*>(&Bs[0][n][k8]) =
            *reinterpret_cast<const short8*>(&Bhg[(size_t)(n0 + n) * K + k8]);
        *reinterpret_cast<short8*>(&Bs[1][n][k8]) =
            *reinterpret_cast<const short8*>(&Blg[(size_t)(n0 + n) * K + k8]);
    }
    __syncthreads();

    int wv = tid >> 6;
    int lane = tid & 63;
    int ml = lane & 15;
    int quad = lane >> 4;
    int mrow0 = m0 + wv * 32;

    floatx4 acc[2][NT];
#pragma unroll
    for (int mt = 0; mt < 2; ++mt)
#pragma unroll
        for (int nt = 0; nt < NT; ++nt) acc[mt][nt] = (floatx4){0.f, 0.f, 0.f, 0.f};

    int arow[2];
#pragma unroll
    for (int mt = 0; mt < 2; ++mt) arow[mt] = min(mrow0 + mt * 16 + ml, M - 1);

    if (!TRANS) {
        short8 ah[2][KT], al[2][KT];
#pragma unroll
        for (int mt = 0; mt < 2; ++mt)
#pragma unroll
            for (int kt = 0; kt < KT; ++kt) {
                size_t aoff = (size_t)arow[mt] * K + kt * 32 + quad * 8;
                ah[mt][kt] = *reinterpret_cast<const short8*>(&Ahg[aoff]);
                al[mt][kt] = *reinterpret_cast<const short8*>(&Alg[aoff]);
            }
#pragma unroll
        for (int kt = 0; kt < KT; ++kt)
#pragma unroll
            for (int nt = 0; nt < NT; ++nt) {
                short8 bh = *reinterpret_cast<const short8*>(&Bs[0][nt * 16 + ml][kt * 32 + quad * 8]);
                short8 bl = *reinterpret_cast<const short8*>(&Bs[1][nt * 16 + ml][kt * 32 + quad * 8]);
#pragma unroll
                for (int mt = 0; mt < 2; ++mt) {
                    acc[mt][nt] = __builtin_amdgcn_mfma_f32_16x16x32_bf16(ah[mt][kt], bh, acc[mt][nt], 0, 0, 0);
                    acc[mt][nt] = __builtin_amdgcn_mfma_f32_16x16x32_bf16(al[mt][kt], bh, acc[mt][nt], 0, 0, 0);
                    acc[mt][nt] = __builtin_amdgcn_mfma_f32_16x16x32_bf16(ah[mt][kt], bl, acc[mt][nt], 0, 0, 0);
                }
            }
    } else {
        short8 ah[2][2], al[2][2];
        auto loadA = [&](int kt, int buf) {
#pragma unroll
            for (int mt = 0; mt < 2; ++mt) {
                const float* ap = &Afp[(size_t)arow[mt] * K + kt * 32 + quad * 8];
                float4 v0 = *reinterpret_cast<const float4*>(ap);
                float4 v1 = *reinterpret_cast<const float4*>(ap + 4);
                int kg = kt * 32 + quad * 8;
                float4 s0 = *reinterpret_cast<const float4*>(&sL[kg]);
                float4 s1 = *reinterpret_cast<const float4*>(&sL[kg + 4]);
                float4 h0 = *reinterpret_cast<const float4*>(&shL[kg]);
                float4 h1 = *reinterpret_cast<const float4*>(&shL[kg + 4]);
                float vv[8] = {
                    fmaxf(fmaf(v0.x, s0.x, h0.x), 0.f), fmaxf(fmaf(v0.y, s0.y, h0.y), 0.f),
                    fmaxf(fmaf(v0.z, s0.z, h0.z), 0.f), fmaxf(fmaf(v0.w, s0.w, h0.w), 0.f),
                    fmaxf(fmaf(v1.x, s1.x, h1.x), 0.f), fmaxf(fmaf(v1.y, s1.y, h1.y), 0.f),
                    fmaxf(fmaf(v1.z, s1.z, h1.z), 0.f), fmaxf(fmaf(v1.w, s1.w, h1.w), 0.f)};
                short8 hv, lv;
#pragma unroll
                for (int q = 0; q < 8; ++q) {
                    short hb, lb;
                    fsplit(vv[q], hb, lb);
                    hv[q] = hb;
                    lv[q] = lb;
                }
                ah[mt][buf] = hv;
                al[mt][buf] = lv;
            }
        };
        loadA(0, 0);
        for (int kt = 0; kt < KT; ++kt) {
            int cur = kt & 1;
            if (kt + 1 < KT) loadA(kt + 1, cur ^ 1);
#pragma unroll
            for (int nt = 0; nt < NT; ++nt) {
                short8 bh = *reinterpret_cast<const short8*>(&Bs[0][nt * 16 + ml][kt * 32 + quad * 8]);
                short8 bl = *reinterpret_cast<const short8*>(&Bs[1][nt * 16 + ml][kt * 32 + quad * 8]);
#pragma unroll
                for (int mt = 0; mt < 2; ++mt) {
                    acc[mt][nt] = __builtin_amdgcn_mfma_f32_16x16x32_bf16(ah[mt][cur], bh, acc[mt][nt], 0, 0, 0);
                    acc[mt][nt] = __builtin_amdgcn_mfma_f32_16x16x32_bf16(al[mt][cur], bh, acc[mt][nt], 0, 0, 0);
                    acc[mt][nt] = __builtin_amdgcn_mfma_f32_16x16x32_bf16(ah[mt][cur], bl, acc[mt][nt], 0, 0, 0);
                }
            }
        }
    }

    // epilogue: bias + store; stats reduced across quads via shfl first
#pragma unroll
    for (int nt = 0; nt < NT; ++nt) {
        int col = nt * 16 + ml;
        float bv = bias[n0 + col];
        float cs = 0.f, cq = 0.f;
#pragma unroll
        for (int mt = 0; mt < 2; ++mt)
#pragma unroll
            for (int r = 0; r < 4; ++r) {
                int m = mrow0 + mt * 16 + quad * 4 + r;
                if (m < M) {
                    float v = acc[mt][nt][r] + bv;
                    C[(size_t)m * NFULL + n0 + col] = v;
                    cs += v; cq += v * v;
                }
            }
        cs += __shfl(cs, lane ^ 16); cq += __shfl(cq, lane ^ 16);
        cs += __shfl(cs, lane ^ 32); cq += __shfl(cq, lane ^ 32);
        if (quad == 0) {
            atomicAdd(&scol[col], cs);
            atomicAdd(&sqcol[col], cq);
        }
    }
    __syncthreads();
    if (tid < NPANEL) {
        atomicAdd(&sums[n0 + tid], scol[tid]);
        atomicAdd(&sqs[n0 + tid], sqcol[tid]);
    }
}

// ---------------- fused pool (BN+ReLU folded) + LSTM + linear ----------------
__global__ __launch_bounds__(256) void pool_lstm_kernel(
    const float* __restrict__ h, const int* __restrict__ batch,
    const float* __restrict__ sums, const float* __restrict__ sqs,
    const float* __restrict__ g, const float* __restrict__ bb,
    const float* __restrict__ wih, const float* __restrict__ bih,
    const float* __restrict__ bhh, const float* __restrict__ lin_w,
    const float* __restrict__ lin_b, float* __restrict__ out) {
    __shared__ int range[2];
    __shared__ float acc2[256];
    __shared__ float pr[HD];
    __shared__ float gates[4 * LHID];
    __shared__ float hh[LHID];
    int gid = blockIdx.x;
    int tid = threadIdx.x;
    if (tid < 2) {
        int target = gid + tid;
        int lo = 0, hi = NNODES;
        while (lo < hi) {
            int mid = (lo + hi) >> 1;
            if (batch[mid] < target) lo = mid + 1; else hi = mid;
        }
        range[tid] = lo;
    }
    __syncthreads();
    int s0 = range[0], s1 = range[1];
    int c = tid & 127;
    int half = tid >> 7;
    float mu = sums[c] * INVN;
    float var = fmaxf(sqs[c] * INVN - mu * mu, 0.f);
    float is = rsqrtf(var + 1e-5f);
    float sc = g[c] * is;
    float sh = bb[c] - mu * sc;
    float a = 0.f;
    for (int r = s0 + half; r < s1; r += 2)
        a += fmaxf(fmaf(h[(size_t)r * HD + c], sc, sh), 0.f);
    acc2[tid] = a;
    __syncthreads();
    if (half == 0) pr[c] = acc2[c] + acc2[c + 128];
    __syncthreads();
    {
        float acc = bih[tid] + bhh[tid];
        const float* wr = wih + tid * HD;
        for (int k = 0; k < HD; ++k) acc += pr[k] * wr[k];
        gates[tid] = acc;
    }
    __syncthreads();
    if (tid < LHID) {
        float ig = gates[tid];
        float gg = gates[2 * LHID + tid];
        float og = gates[3 * LHID + tid];
        float cc = (1.f / (1.f + __expf(-ig))) * tanhf(gg);
        hh[tid] = (1.f / (1.f + __expf(-og))) * tanhf(cc);
    }
    __syncthreads();
    if (tid < COUT) {
        float acc = lin_b[tid];
        const float* lr = lin_w + tid * LHID;
        for (int k = 0; k < LHID; ++k) acc += hh[k] * lr[k];
        out[gid * COUT + tid] = acc;
    }
}

extern "C" void kernel_launch(void* const* d_in, const int* in_sizes, int n_in,
                              void* d_out, int out_size, void* d_ws, size_t ws_size,
                              hipStream_t stream) {
    const float* x        = (const float*)d_in[0];
    const float* ncc      = (const float*)d_in[1];
    const int*   eidx     = (const int*)d_in[2];
    const int*   eattr    = (const int*)d_in[3];
    const int*   batch    = (const int*)d_in[4];
    const float* fc_w     = (const float*)d_in[5];
    const float* fc_b     = (const float*)d_in[6];
    const float* edge_emb = (const float*)d_in[7];
    const float* conv_w1  = (const float*)d_in[8];
    const float* conv_b1  = (const float*)d_in[9];
    const float* conv_bn_g= (const float*)d_in[10];
    const float* conv_bn_b= (const float*)d_in[11];
    const float* conv_w2  = (const float*)d_in[12];
    const float* conv_b2  = (const float*)d_in[13];
    const float* bn_g     = (const float*)d_in[14];
    const float* bn_b     = (const float*)d_in[15];
    const float* lstm_wih = (const float*)d_in[16];
    const float* lstm_bih = (const float*)d_in[18];
    const float* lstm_bhh = (const float*)d_in[19];
    const float* lin_w    = (const float*)d_in[20];
    const float* lin_b    = (const float*)d_in[21];
    float* out = (float*)d_out;

    const int* src = eidx;
    const int* dst = eidx + NEDGES;

    char* ws = (char*)d_ws;
    size_t o = 0;
    auto alloc = [&](size_t bytes) {
        size_t r = o;
        o += (bytes + 255) & ~(size_t)255;
        return r;
    };
    int*   deg    = (int*)(ws + alloc(NNODES * 4));
    int*   off    = (int*)(ws + alloc((NNODES + 1) * 4));
    int*   cursor = (int*)(ws + alloc(NNODES * 4));
    int*   pedge  = (int*)(ws + alloc(NEDGES * 4));
    int*   bsum   = (int*)(ws + alloc(256 * 4));
    int*   bpre   = (int*)(ws + alloc(256 * 4));
    float* h      = (float*)(ws + alloc((size_t)NNODES * HD * 4));
    short* x0h    = (short*)(ws + alloc((size_t)NNODES * HD * 2));
    short* x0l    = (short*)(ws + alloc((size_t)NNODES * HD * 2));
    float* xmid   = (float*)(ws + alloc((size_t)NNODES * 2 * HD * 4));
    short* w1h    = (short*)(ws + alloc((size_t)NLAYER * 2 * HD * HD * 2));
    short* w1l    = (short*)(ws + alloc((size_t)NLAYER * 2 * HD * HD * 2));
    short* w2h    = (short*)(ws + alloc((size_t)NLAYER * 2 * HD * HD * 2));
    short* w2l    = (short*)(ws + alloc((size_t)NLAYER * 2 * HD * HD * 2));
    float* stats  = (float*)(ws + alloc(NLAYER * 768 * 4));

    // ---- CSR build + weight split ----
    hipMemsetAsync(deg, 0, NNODES * 4, stream);
    hipMemsetAsync(stats, 0, NLAYER * 768 * 4, stream);
    hist_kernel<<<(NEDGES + 255) / 256, 256, 0, stream>>>(dst, deg, NEDGES);
    blocksum_kernel<<<SCAN_BLOCKS, 256, 0, stream>>>(deg, bsum);
    scanpartials_kernel<<<1, 256, 0, stream>>>(bsum, bpre);
    writeoff_kernel<<<SCAN_BLOCKS, 256, 0, stream>>>(deg, bpre, off, cursor);
    scatter_kernel<<<(NEDGES + 255) / 256, 256, 0, stream>>>(src, dst, eattr, cursor, pedge, NEDGES);
    wsplit_kernel<<<(NLAYER * 2 * HD * HD + 255) / 256, 256, 0, stream>>>(
        conv_w1, conv_w2, w1h, w1l, w2h, w2l);

    // ---- input FC ----
    fc_kernel<<<NNODES / 8, 256, 0, stream>>>(x, ncc, fc_w, fc_b, h);

    const int gemmGridX = (NNODES + 255) / 256;
    for (int l = 0; l < NLAYER; ++l) {
        float* sumsA = stats + l * 768;
        float* sqsA  = sumsA + 256;
        float* sumsB = sumsA + 512;
        float* sqsB  = sumsA + 640;
        if (l == 0)
            agg_kernel<false><<<NNODES / 4, 256, 0, stream>>>(
                h, off, pedge, edge_emb, nullptr, nullptr, nullptr, nullptr, x0h, x0l);
        else {
            float* pB = stats + (l - 1) * 768;
            agg_kernel<true><<<NNODES / 4, 256, 0, stream>>>(
                h, off, pedge, edge_emb, pB + 512, pB + 640,
                bn_g + (l - 1) * HD, bn_b + (l - 1) * HD, x0h, x0l);
        }
        gemm_kernel<128, 4, 256, false><<<dim3(gemmGridX, 2), 512, 0, stream>>>(
            x0h, x0l, nullptr,
            w1h + (size_t)l * 2 * HD * HD, w1l + (size_t)l * 2 * HD * HD,
            conv_b1 + l * 2 * HD,
            nullptr, nullptr, nullptr, nullptr,
            xmid, sumsA, sqsA, NNODES);
        gemm_kernel<64, 8, 128, true><<<dim3(gemmGridX, 2), 512, 0, stream>>>(
            nullptr, nullptr, xmid,
            w2h + (size_t)l * 2 * HD * HD, w2l + (size_t)l * 2 * HD * HD,
            conv_b2 + l * HD,
            sumsA, sqsA, conv_bn_g + l * 2 * HD, conv_bn_b + l * 2 * HD,
            h, sumsB, sqsB, NNODES);
    }

    {
        float* pB = stats + (NLAYER - 1) * 768;
        pool_lstm_kernel<<<NGRAPH, 256, 0, stream>>>(
            h, batch, pB + 512, pB + 640,
            bn_g + (NLAYER - 1) * HD, bn_b + (NLAYER - 1) * HD,
            lstm_wih, lstm_bih, lstm_bhh, lin_w, lin_b, out);
    }
}

// Round 15
// 856.624 us; speedup vs baseline: 1.0342x; 1.0342x over previous
//
#include <hip/hip_runtime.h>
#include <hip/hip_bf16.h>
#include <hip/hip_fp16.h>
#include <math.h>

#define NNODES 50000
#define NEDGES 640000
#define NGRAPH 256
#define CIN 32
#define HD 128
#define NLAYER 5
#define LHID 64
#define COUT 10
#define EPS_GEN 1e-7f
#define INVN (1.f / (float)NNODES)
#define SCAN_BLOCKS 196

typedef __attribute__((ext_vector_type(8))) short short8;
typedef __attribute__((ext_vector_type(4))) float floatx4;
typedef __attribute__((ext_vector_type(4))) _Float16 half4v;

// truncating compensated split: v ~= bf(hi) + bf(lo)
__device__ __forceinline__ void fsplit(float v, short &hi, short &lo) {
    union { float f; unsigned u; } a; a.f = v;
    hi = (short)(a.u >> 16);
    union { unsigned u; float f; } b; b.u = a.u & 0xFFFF0000u;
    union { float f; unsigned u; } c; c.f = v - b.f;
    lo = (short)(c.u >> 16);
}

// ---------------- CSR build ----------------
__global__ void hist_kernel(const int* __restrict__ dst, int* __restrict__ deg, int e) {
    int i = blockIdx.x * blockDim.x + threadIdx.x;
    if (i < e) atomicAdd(&deg[dst[i]], 1);
}

__global__ void blocksum_kernel(const int* __restrict__ deg, int* __restrict__ bsum) {
    int i = blockIdx.x * 256 + threadIdx.x;
    int v = (i < NNODES) ? deg[i] : 0;
#pragma unroll
    for (int d = 32; d; d >>= 1) v += __shfl_down(v, d);
    __shared__ int ws4[4];
    if ((threadIdx.x & 63) == 0) ws4[threadIdx.x >> 6] = v;
    __syncthreads();
    if (threadIdx.x == 0) bsum[blockIdx.x] = ws4[0] + ws4[1] + ws4[2] + ws4[3];
}

__global__ void scanpartials_kernel(const int* __restrict__ bsum, int* __restrict__ bpre) {
    __shared__ int t[256];
    int i = threadIdx.x;
    t[i] = (i < SCAN_BLOCKS) ? bsum[i] : 0;
    __syncthreads();
    for (int d = 1; d < 256; d <<= 1) {
        int v = (i >= d) ? t[i - d] : 0;
        __syncthreads();
        t[i] += v;
        __syncthreads();
    }
    bpre[i] = (i == 0) ? 0 : t[i - 1];
}

__global__ void writeoff_kernel(const int* __restrict__ deg, const int* __restrict__ bpre,
                                int* __restrict__ off, int* __restrict__ cursor) {
    __shared__ int t[256];
    int tid = threadIdx.x;
    int i = blockIdx.x * 256 + tid;
    int v = (i < NNODES) ? deg[i] : 0;
    t[tid] = v;
    __syncthreads();
    for (int d = 1; d < 256; d <<= 1) {
        int u = (tid >= d) ? t[tid - d] : 0;
        __syncthreads();
        t[tid] += u;
        __syncthreads();
    }
    int excl = bpre[blockIdx.x] + t[tid] - v;
    if (i < NNODES) { off[i] = excl; cursor[i] = excl; }
    if (i == NNODES - 1) off[NNODES] = excl + v;
}

__global__ void scatter_kernel(const int* __restrict__ src, const int* __restrict__ dst,
                               const int* __restrict__ eattr, int* __restrict__ cursor,
                               int* __restrict__ pedge, int e) {
    int i = blockIdx.x * blockDim.x + threadIdx.x;
    if (i < e) {
        int slot = atomicAdd(&cursor[dst[i]], 1);
        pedge[slot] = src[i] | (eattr[i] << 27);
    }
}

// ---------------- weight split (once per launch) ----------------
__global__ void wsplit_kernel(const float* __restrict__ w1, const float* __restrict__ w2,
                              short* __restrict__ w1h, short* __restrict__ w1l,
                              short* __restrict__ w2h, short* __restrict__ w2l) {
    int i = blockIdx.x * 256 + threadIdx.x;
    if (i < NLAYER * 2 * HD * HD) {
        short hi, lo;
        fsplit(w1[i], hi, lo);
        w1h[i] = hi; w1l[i] = lo;
        fsplit(w2[i], hi, lo);
        w2h[i] = hi; w2l[i] = lo;
    }
}

// ---------------- input FC (fp32 h + fp16 mirror) ----------------
__global__ __launch_bounds__(256) void fc_kernel(
    const float* __restrict__ x, const float* __restrict__ ncc,
    const float* __restrict__ w, const float* __restrict__ b,
    float* __restrict__ h, _Float16* __restrict__ hf) {
    __shared__ float ws[HD][41];
    __shared__ float bs[HD];
    int tid = threadIdx.x;
    for (int i = tid; i < HD * 40; i += 256) ws[i / 40][i % 40] = w[i];
    if (tid < HD) bs[tid] = b[tid];
    __syncthreads();
    int c = tid & 127;
    int hi = tid >> 7;
#pragma unroll
    for (int nn = 0; nn < 4; ++nn) {
        int node = blockIdx.x * 8 + nn * 2 + hi;
        const float4* xr = reinterpret_cast<const float4*>(x + (size_t)node * CIN);
        const float4* nr = reinterpret_cast<const float4*>(ncc + (size_t)node * 8);
        float acc = bs[c];
#pragma unroll
        for (int k4 = 0; k4 < 8; ++k4) {
            float4 xv = xr[k4];
            acc += xv.x * ws[c][k4 * 4 + 0];
            acc += xv.y * ws[c][k4 * 4 + 1];
            acc += xv.z * ws[c][k4 * 4 + 2];
            acc += xv.w * ws[c][k4 * 4 + 3];
        }
#pragma unroll
        for (int k4 = 0; k4 < 2; ++k4) {
            float4 nv = nr[k4];
            acc += nv.x * ws[c][32 + k4 * 4 + 0];
            acc += nv.y * ws[c][32 + k4 * 4 + 1];
            acc += nv.z * ws[c][32 + k4 * 4 + 2];
            acc += nv.w * ws[c][32 + k4 * 4 + 3];
        }
        h[(size_t)node * HD + c] = acc;
        hf[(size_t)node * HD + c] = (_Float16)acc;
    }
}

// ---------------- softmax aggregation: fp16 gather, fp32 residual ----------------
template <bool BN>
__global__ __launch_bounds__(256) void agg_kernel(
    const float* __restrict__ h, const _Float16* __restrict__ hf,
    const int* __restrict__ off,
    const int* __restrict__ pedge, const float* __restrict__ edge_emb,
    const float* __restrict__ sums, const float* __restrict__ sqs,
    const float* __restrict__ g, const float* __restrict__ bb,
    short* __restrict__ x0h, short* __restrict__ x0l) {
    __shared__ float ee[4 * HD];
    __shared__ float scs[HD], shs[HD];
    int tid = threadIdx.x;
    ee[tid] = edge_emb[tid];
    ee[tid + 256] = edge_emb[tid + 256];
    if (BN && tid < HD) {
        float mu = sums[tid] * INVN;
        float var = fmaxf(sqs[tid] * INVN - mu * mu, 0.f);
        float is = rsqrtf(var + 1e-5f);
        float sc = g[tid] * is;
        scs[tid] = sc;
        shs[tid] = bb[tid] - mu * sc;
    }
    __syncthreads();

    int node = blockIdx.x * 4 + (tid >> 6);
    int lane = tid & 63;
    int half = lane >> 5;
    int c4 = (lane & 31) * 4;

    int b = off[node], e = off[node + 1];
    float4 sc4 = make_float4(1.f, 1.f, 1.f, 1.f);
    float4 sh4 = make_float4(0.f, 0.f, 0.f, 0.f);
    if (BN) {
        sc4 = *reinterpret_cast<const float4*>(&scs[c4]);
        sh4 = *reinterpret_cast<const float4*>(&shs[c4]);
    }
    float4 S = make_float4(0.f, 0.f, 0.f, 0.f);
    float4 T = make_float4(0.f, 0.f, 0.f, 0.f);
    int j = b + half;
    unsigned pnext = (j < e) ? (unsigned)pedge[j] : 0u;
    for (; j < e; j += 2) {
        unsigned p = pnext;
        if (j + 2 < e) pnext = (unsigned)pedge[j + 2];
        int s = p & 0x07FFFFFFu;
        int a = p >> 27;
        half4v uv = *reinterpret_cast<const half4v*>(&hf[(size_t)s * HD + c4]);
        float4 ev = *reinterpret_cast<const float4*>(&ee[a * HD + c4]);
        float4 v = make_float4((float)uv.x, (float)uv.y, (float)uv.z, (float)uv.w);
        if (BN) {
            v.x = fmaxf(fmaf(v.x, sc4.x, sh4.x), 0.f);
            v.y = fmaxf(fmaf(v.y, sc4.y, sh4.y), 0.f);
            v.z = fmaxf(fmaf(v.z, sc4.z, sh4.z), 0.f);
            v.w = fmaxf(fmaf(v.w, sc4.w, sh4.w), 0.f);
        }
        float m0 = fmaxf(v.x + ev.x, 0.f) + EPS_GEN;
        float m1 = fmaxf(v.y + ev.y, 0.f) + EPS_GEN;
        float m2 = fmaxf(v.z + ev.z, 0.f) + EPS_GEN;
        float m3 = fmaxf(v.w + ev.w, 0.f) + EPS_GEN;
        float e0 = __expf(m0), e1 = __expf(m1), e2 = __expf(m2), e3 = __expf(m3);
        S.x += e0; S.y += e1; S.z += e2; S.w += e3;
        T.x = fmaf(e0, m0, T.x); T.y = fmaf(e1, m1, T.y);
        T.z = fmaf(e2, m2, T.z); T.w = fmaf(e3, m3, T.w);
    }
    S.x += __shfl(S.x, lane ^ 32); S.y += __shfl(S.y, lane ^ 32);
    S.z += __shfl(S.z, lane ^ 32); S.w += __shfl(S.w, lane ^ 32);
    T.x += __shfl(T.x, lane ^ 32); T.y += __shfl(T.y, lane ^ 32);
    T.z += __shfl(T.z, lane ^ 32); T.w += __shfl(T.w, lane ^ 32);
    if (half == 0) {
        float4 r = *reinterpret_cast<const float4*>(&h[(size_t)node * HD + c4]);
        if (BN) {
            r.x = fmaxf(fmaf(r.x, sc4.x, sh4.x), 0.f);
            r.y = fmaxf(fmaf(r.y, sc4.y, sh4.y), 0.f);
            r.z = fmaxf(fmaf(r.z, sc4.z, sh4.z), 0.f);
            r.w = fmaxf(fmaf(r.w, sc4.w, sh4.w), 0.f);
        }
        if (e > b) {
            r.x += T.x / S.x; r.y += T.y / S.y;
            r.z += T.z / S.z; r.w += T.w / S.w;
        }
        float vv[4] = {r.x, r.y, r.z, r.w};
        short4 hv, lv;
        short hh4[4], ll4[4];
#pragma unroll
        for (int q = 0; q < 4; ++q) fsplit(vv[q], hh4[q], ll4[q]);
        hv.x = hh4[0]; hv.y = hh4[1]; hv.z = hh4[2]; hv.w = hh4[3];
        lv.x = ll4[0]; lv.y = ll4[1]; lv.z = ll4[2]; lv.w = ll4[3];
        *reinterpret_cast<short4*>(&x0h[(size_t)node * HD + c4]) = hv;
        *reinterpret_cast<short4*>(&x0l[(size_t)node * HD + c4]) = lv;
    }
}

// ---------------- MFMA GEMM: B-stationary LDS, barrier-free compute, 512 thr / BM=256 ----------------
// Chf != nullptr (GEMM2): also write fp16 mirror of C for the next agg's gather.
template <int NPANEL, int KT, int NFULL, bool TRANS>
__global__ __launch_bounds__(512) void gemm_kernel(
    const short* __restrict__ Ahg, const short* __restrict__ Alg,
    const float* __restrict__ Afp,
    const short* __restrict__ Bhg, const short* __restrict__ Blg,
    const float* __restrict__ bias,
    const float* __restrict__ sums_in, const float* __restrict__ sqs_in,
    const float* __restrict__ g_in, const float* __restrict__ b_in,
    float* __restrict__ C, _Float16* __restrict__ Chf,
    float* __restrict__ sums, float* __restrict__ sqs,
    int M) {
    constexpr int K = KT * 32;
    constexpr int BSTRIDE = K + 8;
    constexpr int NT = NPANEL / 16;
    __shared__ short Bs[2][NPANEL][BSTRIDE];
    __shared__ float scol[NPANEL], sqcol[NPANEL];
    __shared__ float sL[256], shL[256];
    int tid = threadIdx.x;
    int m0 = blockIdx.x * 256;
    int n0 = blockIdx.y * NPANEL;
    if (tid < NPANEL) { scol[tid] = 0.f; sqcol[tid] = 0.f; }
    if (TRANS && tid < K) {
        float mu = sums_in[tid] * INVN;
        float var = fmaxf(sqs_in[tid] * INVN - mu * mu, 0.f);
        float is = rsqrtf(var + 1e-5f);
        float sc = g_in[tid] * is;
        sL[tid] = sc;
        shL[tid] = b_in[tid] - mu * sc;
    }
    constexpr int ELEMS = NPANEL * (K / 8);
#pragma unroll
    for (int i = tid; i < ELEMS; i += 512) {
        int n = i / (K / 8);
        int k8 = (i % (K / 8)) * 8;
        *reinterpret_cast<short8*>(&Bs[0][n][k8]) =
            *reinterpret_cast<const short8*>(&Bhg[(size_t)(n0 + n) * K + k8]);
        *reinterpret_cast<short8*>(&Bs[1][n][k8]) =
            *reinterpret_cast<const short8*>(&Blg[(size_t)(n0 + n) * K + k8]);
    }
    __syncthreads();

    int wv = tid >> 6;
    int lane = tid & 63;
    int ml = lane & 15;
    int quad = lane >> 4;
    int mrow0 = m0 + wv * 32;

    floatx4 acc[2][NT];
#pragma unroll
    for (int mt = 0; mt < 2; ++mt)
#pragma unroll
        for (int nt = 0; nt < NT; ++nt) acc[mt][nt] = (floatx4){0.f, 0.f, 0.f, 0.f};

    int arow[2];
#pragma unroll
    for (int mt = 0; mt < 2; ++mt) arow[mt] = min(mrow0 + mt * 16 + ml, M - 1);

    if (!TRANS) {
        short8 ah[2][KT], al[2][KT];
#pragma unroll
        for (int mt = 0; mt < 2; ++mt)
#pragma unroll
            for (int kt = 0; kt < KT; ++kt) {
                size_t aoff = (size_t)arow[mt] * K + kt * 32 + quad * 8;
                ah[mt][kt] = *reinterpret_cast<const short8*>(&Ahg[aoff]);
                al[mt][kt] = *reinterpret_cast<const short8*>(&Alg[aoff]);
            }
#pragma unroll
        for (int kt = 0; kt < KT; ++kt)
#pragma unroll
            for (int nt = 0; nt < NT; ++nt) {
                short8 bh = *reinterpret_cast<const short8*>(&Bs[0][nt * 16 + ml][kt * 32 + quad * 8]);
                short8 bl = *reinterpret_cast<const short8*>(&Bs[1][nt * 16 + ml][kt * 32 + quad * 8]);
#pragma unroll
                for (int mt = 0; mt < 2; ++mt) {
                    acc[mt][nt] = __builtin_amdgcn_mfma_f32_16x16x32_bf16(ah[mt][kt], bh, acc[mt][nt], 0, 0, 0);
                    acc[mt][nt] = __builtin_amdgcn_mfma_f32_16x16x32_bf16(al[mt][kt], bh, acc[mt][nt], 0, 0, 0);
                    acc[mt][nt] = __builtin_amdgcn_mfma_f32_16x16x32_bf16(ah[mt][kt], bl, acc[mt][nt], 0, 0, 0);
                }
            }
    } else {
        short8 ah[2][2], al[2][2];
        auto loadA = [&](int kt, int buf) {
#pragma unroll
            for (int mt = 0; mt < 2; ++mt) {
                const float* ap = &Afp[(size_t)arow[mt] * K + kt * 32 + quad * 8];
                float4 v0 = *reinterpret_cast<const float4*>(ap);
                float4 v1 = *reinterpret_cast<const float4*>(ap + 4);
                int kg = kt * 32 + quad * 8;
                float4 s0 = *reinterpret_cast<const float4*>(&sL[kg]);
                float4 s1 = *reinterpret_cast<const float4*>(&sL[kg + 4]);
                float4 h0 = *reinterpret_cast<const float4*>(&shL[kg]);
                float4 h1 = *reinterpret_cast<const float4*>(&shL[kg + 4]);
                float vv[8] = {
                    fmaxf(fmaf(v0.x, s0.x, h0.x), 0.f), fmaxf(fmaf(v0.y, s0.y, h0.y), 0.f),
                    fmaxf(fmaf(v0.z, s0.z, h0.z), 0.f), fmaxf(fmaf(v0.w, s0.w, h0.w), 0.f),
                    fmaxf(fmaf(v1.x, s1.x, h1.x), 0.f), fmaxf(fmaf(v1.y, s1.y, h1.y), 0.f),
                    fmaxf(fmaf(v1.z, s1.z, h1.z), 0.f), fmaxf(fmaf(v1.w, s1.w, h1.w), 0.f)};
                short8 hv, lv;
#pragma unroll
                for (int q = 0; q < 8; ++q) {
                    short hb, lb;
                    fsplit(vv[q], hb, lb);
                    hv[q] = hb;
                    lv[q] = lb;
                }
                ah[mt][buf] = hv;
                al[mt][buf] = lv;
            }
        };
        loadA(0, 0);
        for (int kt = 0; kt < KT; ++kt) {
            int cur = kt & 1;
            if (kt + 1 < KT) loadA(kt + 1, cur ^ 1);
#pragma unroll
            for (int nt = 0; nt < NT; ++nt) {
                short8 bh = *reinterpret_cast<const short8*>(&Bs[0][nt * 16 + ml][kt * 32 + quad * 8]);
                short8 bl = *reinterpret_cast<const short8*>(&Bs[1][nt * 16 + ml][kt * 32 + quad * 8]);
#pragma unroll
                for (int mt = 0; mt < 2; ++mt) {
                    acc[mt][nt] = __builtin_amdgcn_mfma_f32_16x16x32_bf16(ah[mt][cur], bh, acc[mt][nt], 0, 0, 0);
                    acc[mt][nt] = __builtin_amdgcn_mfma_f32_16x16x32_bf16(al[mt][cur], bh, acc[mt][nt], 0, 0, 0);
                    acc[mt][nt] = __builtin_amdgcn_mfma_f32_16x16x32_bf16(ah[mt][cur], bl, acc[mt][nt], 0, 0, 0);
                }
            }
        }
    }

    // epilogue: bias + store (+ fp16 mirror for GEMM2); stats via quad shfl-reduce
#pragma unroll
    for (int nt = 0; nt < NT; ++nt) {
        int col = nt * 16 + ml;
        float bv = bias[n0 + col];
        float cs = 0.f, cq = 0.f;
#pragma unroll
        for (int mt = 0; mt < 2; ++mt)
#pragma unroll
            for (int r = 0; r < 4; ++r) {
                int m = mrow0 + mt * 16 + quad * 4 + r;
                if (m < M) {
                    float v = acc[mt][nt][r] + bv;
                    C[(size_t)m * NFULL + n0 + col] = v;
                    if (Chf) Chf[(size_t)m * NFULL + n0 + col] = (_Float16)v;
                    cs += v; cq += v * v;
                }
            }
        cs += __shfl(cs, lane ^ 16); cq += __shfl(cq, lane ^ 16);
        cs += __shfl(cs, lane ^ 32); cq += __shfl(cq, lane ^ 32);
        if (quad == 0) {
            atomicAdd(&scol[col], cs);
            atomicAdd(&sqcol[col], cq);
        }
    }
    __syncthreads();
    if (tid < NPANEL) {
        atomicAdd(&sums[n0 + tid], scol[tid]);
        atomicAdd(&sqs[n0 + tid], sqcol[tid]);
    }
}

// ---------------- fused pool (BN+ReLU folded) + LSTM + linear ----------------
__global__ __launch_bounds__(256) void pool_lstm_kernel(
    const float* __restrict__ h, const int* __restrict__ batch,
    const float* __restrict__ sums, const float* __restrict__ sqs,
    const float* __restrict__ g, const float* __restrict__ bb,
    const float* __restrict__ wih, const float* __restrict__ bih,
    const float* __restrict__ bhh, const float* __restrict__ lin_w,
    const float* __restrict__ lin_b, float* __restrict__ out) {
    __shared__ int range[2];
    __shared__ float acc2[256];
    __shared__ float pr[HD];
    __shared__ float gates[4 * LHID];
    __shared__ float hh[LHID];
    int gid = blockIdx.x;
    int tid = threadIdx.x;
    if (tid < 2) {
        int target = gid + tid;
        int lo = 0, hi = NNODES;
        while (lo < hi) {
            int mid = (lo + hi) >> 1;
            if (batch[mid] < target) lo = mid + 1; else hi = mid;
        }
        range[tid] = lo;
    }
    __syncthreads();
    int s0 = range[0], s1 = range[1];
    int c = tid & 127;
    int half = tid >> 7;
    float mu = sums[c] * INVN;
    float var = fmaxf(sqs[c] * INVN - mu * mu, 0.f);
    float is = rsqrtf(var + 1e-5f);
    float sc = g[c] * is;
    float sh = bb[c] - mu * sc;
    float a = 0.f;
    for (int r = s0 + half; r < s1; r += 2)
        a += fmaxf(fmaf(h[(size_t)r * HD + c], sc, sh), 0.f);
    acc2[tid] = a;
    __syncthreads();
    if (half == 0) pr[c] = acc2[c] + acc2[c + 128];
    __syncthreads();
    {
        float acc = bih[tid] + bhh[tid];
        const float* wr = wih + tid * HD;
        for (int k = 0; k < HD; ++k) acc += pr[k] * wr[k];
        gates[tid] = acc;
    }
    __syncthreads();
    if (tid < LHID) {
        float ig = gates[tid];
        float gg = gates[2 * LHID + tid];
        float og = gates[3 * LHID + tid];
        float cc = (1.f / (1.f + __expf(-ig))) * tanhf(gg);
        hh[tid] = (1.f / (1.f + __expf(-og))) * tanhf(cc);
    }
    __syncthreads();
    if (tid < COUT) {
        float acc = lin_b[tid];
        const float* lr = lin_w + tid * LHID;
        for (int k = 0; k < LHID; ++k) acc += hh[k] * lr[k];
        out[gid * COUT + tid] = acc;
    }
}

extern "C" void kernel_launch(void* const* d_in, const int* in_sizes, int n_in,
                              void* d_out, int out_size, void* d_ws, size_t ws_size,
                              hipStream_t stream) {
    const float* x        = (const float*)d_in[0];
    const float* ncc      = (const float*)d_in[1];
    const int*   eidx     = (const int*)d_in[2];
    const int*   eattr    = (const int*)d_in[3];
    const int*   batch    = (const int*)d_in[4];
    const float* fc_w     = (const float*)d_in[5];
    const float* fc_b     = (const float*)d_in[6];
    const float* edge_emb = (const float*)d_in[7];
    const float* conv_w1  = (const float*)d_in[8];
    const float* conv_b1  = (const float*)d_in[9];
    const float* conv_bn_g= (const float*)d_in[10];
    const float* conv_bn_b= (const float*)d_in[11];
    const float* conv_w2  = (const float*)d_in[12];
    const float* conv_b2  = (const float*)d_in[13];
    const float* bn_g     = (const float*)d_in[14];
    const float* bn_b     = (const float*)d_in[15];
    const float* lstm_wih = (const float*)d_in[16];
    const float* lstm_bih = (const float*)d_in[18];
    const float* lstm_bhh = (const float*)d_in[19];
    const float* lin_w    = (const float*)d_in[20];
    const float* lin_b    = (const float*)d_in[21];
    float* out = (float*)d_out;

    const int* src = eidx;
    const int* dst = eidx + NEDGES;

    char* ws = (char*)d_ws;
    size_t o = 0;
    auto alloc = [&](size_t bytes) {
        size_t r = o;
        o += (bytes + 255) & ~(size_t)255;
        return r;
    };
    int*   deg    = (int*)(ws + alloc(NNODES * 4));
    int*   off    = (int*)(ws + alloc((NNODES + 1) * 4));
    int*   cursor = (int*)(ws + alloc(NNODES * 4));
    int*   pedge  = (int*)(ws + alloc(NEDGES * 4));
    int*   bsum   = (int*)(ws + alloc(256 * 4));
    int*   bpre   = (int*)(ws + alloc(256 * 4));
    float* h      = (float*)(ws + alloc((size_t)NNODES * HD * 4));
    _Float16* hf  = (_Float16*)(ws + alloc((size_t)NNODES * HD * 2));
    short* x0h    = (short*)(ws + alloc((size_t)NNODES * HD * 2));
    short* x0l    = (short*)(ws + alloc((size_t)NNODES * HD * 2));
    float* xmid   = (float*)(ws + alloc((size_t)NNODES * 2 * HD * 4));
    short* w1h    = (short*)(ws + alloc((size_t)NLAYER * 2 * HD * HD * 2));
    short* w1l    = (short*)(ws + alloc((size_t)NLAYER * 2 * HD * HD * 2));
    short* w2h    = (short*)(ws + alloc((size_t)NLAYER * 2 * HD * HD * 2));
    short* w2l    = (short*)(ws + alloc((size_t)NLAYER * 2 * HD * HD * 2));
    float* stats  = (float*)(ws + alloc(NLAYER * 768 * 4));

    // ---- CSR build + weight split ----
    hipMemsetAsync(deg, 0, NNODES * 4, stream);
    hipMemsetAsync(stats, 0, NLAYER * 768 * 4, stream);
    hist_kernel<<<(NEDGES + 255) / 256, 256, 0, stream>>>(dst, deg, NEDGES);
    blocksum_kernel<<<SCAN_BLOCKS, 256, 0, stream>>>(deg, bsum);
    scanpartials_kernel<<<1, 256, 0, stream>>>(bsum, bpre);
    writeoff_kernel<<<SCAN_BLOCKS, 256, 0, stream>>>(deg, bpre, off, cursor);
    scatter_kernel<<<(NEDGES + 255) / 256, 256, 0, stream>>>(src, dst, eattr, cursor, pedge, NEDGES);
    wsplit_kernel<<<(NLAYER * 2 * HD * HD + 255) / 256, 256, 0, stream>>>(
        conv_w1, conv_w2, w1h, w1l, w2h, w2l);

    // ---- input FC ----
    fc_kernel<<<NNODES / 8, 256, 0, stream>>>(x, ncc, fc_w, fc_b, h, hf);

    const int gemmGridX = (NNODES + 255) / 256;
    for (int l = 0; l < NLAYER; ++l) {
        float* sumsA = stats + l * 768;
        float* sqsA  = sumsA + 256;
        float* sumsB = sumsA + 512;
        float* sqsB  = sumsA + 640;
        if (l == 0)
            agg_kernel<false><<<NNODES / 4, 256, 0, stream>>>(
                h, hf, off, pedge, edge_emb, nullptr, nullptr, nullptr, nullptr, x0h, x0l);
        else {
            float* pB = stats + (l - 1) * 768;
            agg_kernel<true><<<NNODES / 4, 256, 0, stream>>>(
                h, hf, off, pedge, edge_emb, pB + 512, pB + 640,
                bn_g + (l - 1) * HD, bn_b + (l - 1) * HD, x0h, x0l);
        }
        gemm_kernel<128, 4, 256, false><<<dim3(gemmGridX, 2), 512, 0, stream>>>(
            x0h, x0l, nullptr,
            w1h + (size_t)l * 2 * HD * HD, w1l + (size_t)l * 2 * HD * HD,
            conv_b1 + l * 2 * HD,
            nullptr, nullptr, nullptr, nullptr,
            xmid, nullptr, sumsA, sqsA, NNODES);
        gemm_kernel<64, 8, 128, true><<<dim3(gemmGridX, 2), 512, 0, stream>>>(
            nullptr, nullptr, xmid,
            w2h + (size_t)l * 2 * HD * HD, w2l + (size_t)l * 2 * HD * HD,
            conv_b2 + l * HD,
            sumsA, sqsA, conv_bn_g + l * 2 * HD, conv_bn_b + l * 2 * HD,
            h, hf, sumsB, sqsB, NNODES);
    }

    {
        float* pB = stats + (NLAYER - 1) * 768;
        pool_lstm_kernel<<<NGRAPH, 256, 0, stream>>>(
            h, batch, pB + 512, pB + 640,
            bn_g + (NLAYER - 1) * HD, bn_b + (NLAYER - 1) * HD,
            lstm_wih, lstm_bih, lstm_bhh, lin_w, lin_b, out);
    }
}

// Round 16
// 850.119 us; speedup vs baseline: 1.0421x; 1.0077x over previous
//
#include <hip/hip_runtime.h>
#include <hip/hip_bf16.h>
#include <hip/hip_fp16.h>
#include <math.h>

#define NNODES 50000
#define NEDGES 640000
#define NGRAPH 256
#define CIN 32
#define HD 128
#define NLAYER 5
#define LHID 64
#define COUT 10
#define EPS_GEN 1e-7f
#define INVN (1.f / (float)NNODES)
#define SCAN_BLOCKS 196

typedef __attribute__((ext_vector_type(8))) short short8;
typedef __attribute__((ext_vector_type(4))) float floatx4;
typedef __attribute__((ext_vector_type(4))) _Float16 half4v;

// truncating compensated split: v ~= bf(hi) + bf(lo)
__device__ __forceinline__ void fsplit(float v, short &hi, short &lo) {
    union { float f; unsigned u; } a; a.f = v;
    hi = (short)(a.u >> 16);
    union { unsigned u; float f; } b; b.u = a.u & 0xFFFF0000u;
    union { float f; unsigned u; } c; c.f = v - b.f;
    lo = (short)(c.u >> 16);
}

// ---------------- CSR build ----------------
__global__ void hist_kernel(const int* __restrict__ dst, int* __restrict__ deg, int e) {
    int i = blockIdx.x * blockDim.x + threadIdx.x;
    if (i < e) atomicAdd(&deg[dst[i]], 1);
}

__global__ void blocksum_kernel(const int* __restrict__ deg, int* __restrict__ bsum) {
    int i = blockIdx.x * 256 + threadIdx.x;
    int v = (i < NNODES) ? deg[i] : 0;
#pragma unroll
    for (int d = 32; d; d >>= 1) v += __shfl_down(v, d);
    __shared__ int ws4[4];
    if ((threadIdx.x & 63) == 0) ws4[threadIdx.x >> 6] = v;
    __syncthreads();
    if (threadIdx.x == 0) bsum[blockIdx.x] = ws4[0] + ws4[1] + ws4[2] + ws4[3];
}

__global__ void scanpartials_kernel(const int* __restrict__ bsum, int* __restrict__ bpre) {
    __shared__ int t[256];
    int i = threadIdx.x;
    t[i] = (i < SCAN_BLOCKS) ? bsum[i] : 0;
    __syncthreads();
    for (int d = 1; d < 256; d <<= 1) {
        int v = (i >= d) ? t[i - d] : 0;
        __syncthreads();
        t[i] += v;
        __syncthreads();
    }
    bpre[i] = (i == 0) ? 0 : t[i - 1];
}

__global__ void writeoff_kernel(const int* __restrict__ deg, const int* __restrict__ bpre,
                                int* __restrict__ off, int* __restrict__ cursor) {
    __shared__ int t[256];
    int tid = threadIdx.x;
    int i = blockIdx.x * 256 + tid;
    int v = (i < NNODES) ? deg[i] : 0;
    t[tid] = v;
    __syncthreads();
    for (int d = 1; d < 256; d <<= 1) {
        int u = (tid >= d) ? t[tid - d] : 0;
        __syncthreads();
        t[tid] += u;
        __syncthreads();
    }
    int excl = bpre[blockIdx.x] + t[tid] - v;
    if (i < NNODES) { off[i] = excl; cursor[i] = excl; }
    if (i == NNODES - 1) off[NNODES] = excl + v;
}

__global__ void scatter_kernel(const int* __restrict__ src, const int* __restrict__ dst,
                               const int* __restrict__ eattr, int* __restrict__ cursor,
                               int* __restrict__ pedge, int e) {
    int i = blockIdx.x * blockDim.x + threadIdx.x;
    if (i < e) {
        int slot = atomicAdd(&cursor[dst[i]], 1);
        pedge[slot] = src[i] | (eattr[i] << 27);
    }
}

// ---------------- weight split (once per launch) ----------------
__global__ void wsplit_kernel(const float* __restrict__ w1, const float* __restrict__ w2,
                              short* __restrict__ w1h, short* __restrict__ w1l,
                              short* __restrict__ w2h, short* __restrict__ w2l) {
    int i = blockIdx.x * 256 + threadIdx.x;
    if (i < NLAYER * 2 * HD * HD) {
        short hi, lo;
        fsplit(w1[i], hi, lo);
        w1h[i] = hi; w1l[i] = lo;
        fsplit(w2[i], hi, lo);
        w2h[i] = hi; w2l[i] = lo;
    }
}

// ---------------- input FC: weights in VGPRs, broadcast x loads ----------------
// 256 thr: c = tid&127, half = tid>>7; 32 nodes/block, 16 per half.
__global__ __launch_bounds__(256) void fc_kernel(
    const float* __restrict__ x, const float* __restrict__ ncc,
    const float* __restrict__ w, const float* __restrict__ b,
    float* __restrict__ h, _Float16* __restrict__ hf) {
    __shared__ float ws[HD][41];
    int tid = threadIdx.x;
    for (int i = tid; i < HD * 40; i += 256) ws[i / 40][i % 40] = w[i];
    __syncthreads();
    int c = tid & 127;
    int half = tid >> 7;
    float wreg[40];
#pragma unroll
    for (int k = 0; k < 40; ++k) wreg[k] = ws[c][k];   // once; stride-41 rows -> <=2-way banks
    float bc = b[c];
#pragma unroll
    for (int nn = 0; nn < 16; ++nn) {
        int node = blockIdx.x * 32 + nn * 2 + half;
        if (node >= NNODES) break;
        const float4* xr = reinterpret_cast<const float4*>(x + (size_t)node * CIN);
        const float4* nr = reinterpret_cast<const float4*>(ncc + (size_t)node * 8);
        float acc = bc;
#pragma unroll
        for (int k4 = 0; k4 < 8; ++k4) {
            float4 xv = xr[k4];          // broadcast (same addr across lanes)
            acc = fmaf(xv.x, wreg[k4 * 4 + 0], acc);
            acc = fmaf(xv.y, wreg[k4 * 4 + 1], acc);
            acc = fmaf(xv.z, wreg[k4 * 4 + 2], acc);
            acc = fmaf(xv.w, wreg[k4 * 4 + 3], acc);
        }
#pragma unroll
        for (int k4 = 0; k4 < 2; ++k4) {
            float4 nv = nr[k4];
            acc = fmaf(nv.x, wreg[32 + k4 * 4 + 0], acc);
            acc = fmaf(nv.y, wreg[32 + k4 * 4 + 1], acc);
            acc = fmaf(nv.z, wreg[32 + k4 * 4 + 2], acc);
            acc = fmaf(nv.w, wreg[32 + k4 * 4 + 3], acc);
        }
        h[(size_t)node * HD + c] = acc;
        hf[(size_t)node * HD + c] = (_Float16)acc;
    }
}

// ---------------- softmax aggregation: fp16 gather, fp32 residual ----------------
template <bool BN>
__global__ __launch_bounds__(256) void agg_kernel(
    const float* __restrict__ h, const _Float16* __restrict__ hf,
    const int* __restrict__ off,
    const int* __restrict__ pedge, const float* __restrict__ edge_emb,
    const float* __restrict__ sums, const float* __restrict__ sqs,
    const float* __restrict__ g, const float* __restrict__ bb,
    short* __restrict__ x0h, short* __restrict__ x0l) {
    __shared__ float ee[4 * HD];
    __shared__ float scs[HD], shs[HD];
    int tid = threadIdx.x;
    ee[tid] = edge_emb[tid];
    ee[tid + 256] = edge_emb[tid + 256];
    if (BN && tid < HD) {
        float mu = sums[tid] * INVN;
        float var = fmaxf(sqs[tid] * INVN - mu * mu, 0.f);
        float is = rsqrtf(var + 1e-5f);
        float sc = g[tid] * is;
        scs[tid] = sc;
        shs[tid] = bb[tid] - mu * sc;
    }
    __syncthreads();

    int node = blockIdx.x * 4 + (tid >> 6);
    int lane = tid & 63;
    int half = lane >> 5;
    int c4 = (lane & 31) * 4;

    int b = off[node], e = off[node + 1];
    float4 sc4 = make_float4(1.f, 1.f, 1.f, 1.f);
    float4 sh4 = make_float4(0.f, 0.f, 0.f, 0.f);
    if (BN) {
        sc4 = *reinterpret_cast<const float4*>(&scs[c4]);
        sh4 = *reinterpret_cast<const float4*>(&shs[c4]);
    }
    float4 S = make_float4(0.f, 0.f, 0.f, 0.f);
    float4 T = make_float4(0.f, 0.f, 0.f, 0.f);
    int j = b + half;
    unsigned pnext = (j < e) ? (unsigned)pedge[j] : 0u;
    for (; j < e; j += 2) {
        unsigned p = pnext;
        if (j + 2 < e) pnext = (unsigned)pedge[j + 2];
        int s = p & 0x07FFFFFFu;
        int a = p >> 27;
        half4v uv = *reinterpret_cast<const half4v*>(&hf[(size_t)s * HD + c4]);
        float4 ev = *reinterpret_cast<const float4*>(&ee[a * HD + c4]);
        float4 v = make_float4((float)uv.x, (float)uv.y, (float)uv.z, (float)uv.w);
        if (BN) {
            v.x = fmaxf(fmaf(v.x, sc4.x, sh4.x), 0.f);
            v.y = fmaxf(fmaf(v.y, sc4.y, sh4.y), 0.f);
            v.z = fmaxf(fmaf(v.z, sc4.z, sh4.z), 0.f);
            v.w = fmaxf(fmaf(v.w, sc4.w, sh4.w), 0.f);
        }
        float m0 = fmaxf(v.x + ev.x, 0.f) + EPS_GEN;
        float m1 = fmaxf(v.y + ev.y, 0.f) + EPS_GEN;
        float m2 = fmaxf(v.z + ev.z, 0.f) + EPS_GEN;
        float m3 = fmaxf(v.w + ev.w, 0.f) + EPS_GEN;
        float e0 = __expf(m0), e1 = __expf(m1), e2 = __expf(m2), e3 = __expf(m3);
        S.x += e0; S.y += e1; S.z += e2; S.w += e3;
        T.x = fmaf(e0, m0, T.x); T.y = fmaf(e1, m1, T.y);
        T.z = fmaf(e2, m2, T.z); T.w = fmaf(e3, m3, T.w);
    }
    S.x += __shfl(S.x, lane ^ 32); S.y += __shfl(S.y, lane ^ 32);
    S.z += __shfl(S.z, lane ^ 32); S.w += __shfl(S.w, lane ^ 32);
    T.x += __shfl(T.x, lane ^ 32); T.y += __shfl(T.y, lane ^ 32);
    T.z += __shfl(T.z, lane ^ 32); T.w += __shfl(T.w, lane ^ 32);
    if (half == 0) {
        float4 r = *reinterpret_cast<const float4*>(&h[(size_t)node * HD + c4]);
        if (BN) {
            r.x = fmaxf(fmaf(r.x, sc4.x, sh4.x), 0.f);
            r.y = fmaxf(fmaf(r.y, sc4.y, sh4.y), 0.f);
            r.z = fmaxf(fmaf(r.z, sc4.z, sh4.z), 0.f);
            r.w = fmaxf(fmaf(r.w, sc4.w, sh4.w), 0.f);
        }
        if (e > b) {
            r.x += T.x / S.x; r.y += T.y / S.y;
            r.z += T.z / S.z; r.w += T.w / S.w;
        }
        float vv[4] = {r.x, r.y, r.z, r.w};
        short4 hv, lv;
        short hh4[4], ll4[4];
#pragma unroll
        for (int q = 0; q < 4; ++q) fsplit(vv[q], hh4[q], ll4[q]);
        hv.x = hh4[0]; hv.y = hh4[1]; hv.z = hh4[2]; hv.w = hh4[3];
        lv.x = ll4[0]; lv.y = ll4[1]; lv.z = ll4[2]; lv.w = ll4[3];
        *reinterpret_cast<short4*>(&x0h[(size_t)node * HD + c4]) = hv;
        *reinterpret_cast<short4*>(&x0l[(size_t)node * HD + c4]) = lv;
    }
}

// ---------------- MFMA GEMM: B-stationary LDS, barrier-free compute, 512 thr / BM=256 ----------------
template <int NPANEL, int KT, int NFULL, bool TRANS>
__global__ __launch_bounds__(512) void gemm_kernel(
    const short* __restrict__ Ahg, const short* __restrict__ Alg,
    const float* __restrict__ Afp,
    const short* __restrict__ Bhg, const short* __restrict__ Blg,
    const float* __restrict__ bias,
    const float* __restrict__ sums_in, const float* __restrict__ sqs_in,
    const float* __restrict__ g_in, const float* __restrict__ b_in,
    float* __restrict__ C, _Float16* __restrict__ Chf,
    float* __restrict__ sums, float* __restrict__ sqs,
    int M) {
    constexpr int K = KT * 32;
    constexpr int BSTRIDE = K + 8;
    constexpr int NT = NPANEL / 16;
    __shared__ short Bs[2][NPANEL][BSTRIDE];
    __shared__ float scol[NPANEL], sqcol[NPANEL];
    __shared__ float sL[256], shL[256];
    int tid = threadIdx.x;
    int m0 = blockIdx.x * 256;
    int n0 = blockIdx.y * NPANEL;
    if (tid < NPANEL) { scol[tid] = 0.f; sqcol[tid] = 0.f; }
    if (TRANS && tid < K) {
        float mu = sums_in[tid] * INVN;
        float var = fmaxf(sqs_in[tid] * INVN - mu * mu, 0.f);
        float is = rsqrtf(var + 1e-5f);
        float sc = g_in[tid] * is;
        sL[tid] = sc;
        shL[tid] = b_in[tid] - mu * sc;
    }
    constexpr int ELEMS = NPANEL * (K / 8);
#pragma unroll
    for (int i = tid; i < ELEMS; i += 512) {
        int n = i / (K / 8);
        int k8 = (i % (K / 8)) * 8;
        *reinterpret_cast<short8*>(&Bs[0][n][k8]) =
            *reinterpret_cast<const short8*>(&Bhg[(size_t)(n0 + n) * K + k8]);
        *reinterpret_cast<short8*>(&Bs[1][n][k8]) =
            *reinterpret_cast<const short8*>(&Blg[(size_t)(n0 + n) * K + k8]);
    }
    __syncthreads();

    int wv = tid >> 6;
    int lane = tid & 63;
    int ml = lane & 15;
    int quad = lane >> 4;
    int mrow0 = m0 + wv * 32;

    floatx4 acc[2][NT];
#pragma unroll
    for (int mt = 0; mt < 2; ++mt)
#pragma unroll
        for (int nt = 0; nt < NT; ++nt) acc[mt][nt] = (floatx4){0.f, 0.f, 0.f, 0.f};

    int arow[2];
#pragma unroll
    for (int mt = 0; mt < 2; ++mt) arow[mt] = min(mrow0 + mt * 16 + ml, M - 1);

    if (!TRANS) {
        short8 ah[2][KT], al[2][KT];
#pragma unroll
        for (int mt = 0; mt < 2; ++mt)
#pragma unroll
            for (int kt = 0; kt < KT; ++kt) {
                size_t aoff = (size_t)arow[mt] * K + kt * 32 + quad * 8;
                ah[mt][kt] = *reinterpret_cast<const short8*>(&Ahg[aoff]);
                al[mt][kt] = *reinterpret_cast<const short8*>(&Alg[aoff]);
            }
#pragma unroll
        for (int kt = 0; kt < KT; ++kt)
#pragma unroll
            for (int nt = 0; nt < NT; ++nt) {
                short8 bh = *reinterpret_cast<const short8*>(&Bs[0][nt * 16 + ml][kt * 32 + quad * 8]);
                short8 bl = *reinterpret_cast<const short8*>(&Bs[1][nt * 16 + ml][kt * 32 + quad * 8]);
#pragma unroll
                for (int mt = 0; mt < 2; ++mt) {
                    acc[mt][nt] = __builtin_amdgcn_mfma_f32_16x16x32_bf16(ah[mt][kt], bh, acc[mt][nt], 0, 0, 0);
                    acc[mt][nt] = __builtin_amdgcn_mfma_f32_16x16x32_bf16(al[mt][kt], bh, acc[mt][nt], 0, 0, 0);
                    acc[mt][nt] = __builtin_amdgcn_mfma_f32_16x16x32_bf16(ah[mt][kt], bl, acc[mt][nt], 0, 0, 0);
                }
            }
    } else {
        short8 ah[2][2], al[2][2];
        auto loadA = [&](int kt, int buf) {
#pragma unroll
            for (int mt = 0; mt < 2; ++mt) {
                const float* ap = &Afp[(size_t)arow[mt] * K + kt * 32 + quad * 8];
                float4 v0 = *reinterpret_cast<const float4*>(ap);
                float4 v1 = *reinterpret_cast<const float4*>(ap + 4);
                int kg = kt * 32 + quad * 8;
                float4 s0 = *reinterpret_cast<const float4*>(&sL[kg]);
                float4 s1 = *reinterpret_cast<const float4*>(&sL[kg + 4]);
                float4 h0 = *reinterpret_cast<const float4*>(&shL[kg]);
                float4 h1 = *reinterpret_cast<const float4*>(&shL[kg + 4]);
                float vv[8] = {
                    fmaxf(fmaf(v0.x, s0.x, h0.x), 0.f), fmaxf(fmaf(v0.y, s0.y, h0.y), 0.f),
                    fmaxf(fmaf(v0.z, s0.z, h0.z), 0.f), fmaxf(fmaf(v0.w, s0.w, h0.w), 0.f),
                    fmaxf(fmaf(v1.x, s1.x, h1.x), 0.f), fmaxf(fmaf(v1.y, s1.y, h1.y), 0.f),
                    fmaxf(fmaf(v1.z, s1.z, h1.z), 0.f), fmaxf(fmaf(v1.w, s1.w, h1.w), 0.f)};
                short8 hv, lv;
#pragma unroll
                for (int q = 0; q < 8; ++q) {
                    short hb, lb;
                    fsplit(vv[q], hb, lb);
                    hv[q] = hb;
                    lv[q] = lb;
                }
                ah[mt][buf] = hv;
                al[mt][buf] = lv;
            }
        };
        loadA(0, 0);
        for (int kt = 0; kt < KT; ++kt) {
            int cur = kt & 1;
            if (kt + 1 < KT) loadA(kt + 1, cur ^ 1);
#pragma unroll
            for (int nt = 0; nt < NT; ++nt) {
                short8 bh = *reinterpret_cast<const short8*>(&Bs[0][nt * 16 + ml][kt * 32 + quad * 8]);
                short8 bl = *reinterpret_cast<const short8*>(&Bs[1][nt * 16 + ml][kt * 32 + quad * 8]);
#pragma unroll
                for (int mt = 0; mt < 2; ++mt) {
                    acc[mt][nt] = __builtin_amdgcn_mfma_f32_16x16x32_bf16(ah[mt][cur], bh, acc[mt][nt], 0, 0, 0);
                    acc[mt][nt] = __builtin_amdgcn_mfma_f32_16x16x32_bf16(al[mt][cur], bh, acc[mt][nt], 0, 0, 0);
                    acc[mt][nt] = __builtin_amdgcn_mfma_f32_16x16x32_bf16(ah[mt][cur], bl, acc[mt][nt], 0, 0, 0);
                }
            }
        }
    }

    // epilogue: bias + store (+ fp16 mirror for GEMM2); stats via quad shfl-reduce
#pragma unroll
    for (int nt = 0; nt < NT; ++nt) {
        int col = nt * 16 + ml;
        float bv = bias[n0 + col];
        float cs = 0.f, cq = 0.f;
#pragma unroll
        for (int mt = 0; mt < 2; ++mt)
#pragma unroll
            for (int r = 0; r < 4; ++r) {
                int m = mrow0 + mt * 16 + quad * 4 + r;
                if (m < M) {
                    float v = acc[mt][nt][r] + bv;
                    C[(size_t)m * NFULL + n0 + col] = v;
                    if (Chf) Chf[(size_t)m * NFULL + n0 + col] = (_Float16)v;
                    cs += v; cq += v * v;
                }
            }
        cs += __shfl(cs, lane ^ 16); cq += __shfl(cq, lane ^ 16);
        cs += __shfl(cs, lane ^ 32); cq += __shfl(cq, lane ^ 32);
        if (quad == 0) {
            atomicAdd(&scol[col], cs);
            atomicAdd(&sqcol[col], cq);
        }
    }
    __syncthreads();
    if (tid < NPANEL) {
        atomicAdd(&sums[n0 + tid], scol[tid]);
        atomicAdd(&sqs[n0 + tid], sqcol[tid]);
    }
}

// ---------------- fused pool (BN+ReLU folded) + LSTM + linear ----------------
__global__ __launch_bounds__(256) void pool_lstm_kernel(
    const float* __restrict__ h, const int* __restrict__ batch,
    const float* __restrict__ sums, const float* __restrict__ sqs,
    const float* __restrict__ g, const float* __restrict__ bb,
    const float* __restrict__ wih, const float* __restrict__ bih,
    const float* __restrict__ bhh, const float* __restrict__ lin_w,
    const float* __restrict__ lin_b, float* __restrict__ out) {
    __shared__ int range[2];
    __shared__ float acc2[256];
    __shared__ float pr[HD];
    __shared__ float gates[4 * LHID];
    __shared__ float hh[LHID];
    int gid = blockIdx.x;
    int tid = threadIdx.x;
    if (tid < 2) {
        int target = gid + tid;
        int lo = 0, hi = NNODES;
        while (lo < hi) {
            int mid = (lo + hi) >> 1;
            if (batch[mid] < target) lo = mid + 1; else hi = mid;
        }
        range[tid] = lo;
    }
    __syncthreads();
    int s0 = range[0], s1 = range[1];
    int c = tid & 127;
    int half = tid >> 7;
    float mu = sums[c] * INVN;
    float var = fmaxf(sqs[c] * INVN - mu * mu, 0.f);
    float is = rsqrtf(var + 1e-5f);
    float sc = g[c] * is;
    float sh = bb[c] - mu * sc;
    float a = 0.f;
    for (int r = s0 + half; r < s1; r += 2)
        a += fmaxf(fmaf(h[(size_t)r * HD + c], sc, sh), 0.f);
    acc2[tid] = a;
    __syncthreads();
    if (half == 0) pr[c] = acc2[c] + acc2[c + 128];
    __syncthreads();
    {
        float acc = bih[tid] + bhh[tid];
        const float* wr = wih + tid * HD;
        for (int k = 0; k < HD; ++k) acc += pr[k] * wr[k];
        gates[tid] = acc;
    }
    __syncthreads();
    if (tid < LHID) {
        float ig = gates[tid];
        float gg = gates[2 * LHID + tid];
        float og = gates[3 * LHID + tid];
        float cc = (1.f / (1.f + __expf(-ig))) * tanhf(gg);
        hh[tid] = (1.f / (1.f + __expf(-og))) * tanhf(cc);
    }
    __syncthreads();
    if (tid < COUT) {
        float acc = lin_b[tid];
        const float* lr = lin_w + tid * LHID;
        for (int k = 0; k < LHID; ++k) acc += hh[k] * lr[k];
        out[gid * COUT + tid] = acc;
    }
}

extern "C" void kernel_launch(void* const* d_in, const int* in_sizes, int n_in,
                              void* d_out, int out_size, void* d_ws, size_t ws_size,
                              hipStream_t stream) {
    const float* x        = (const float*)d_in[0];
    const float* ncc      = (const float*)d_in[1];
    const int*   eidx     = (const int*)d_in[2];
    const int*   eattr    = (const int*)d_in[3];
    const int*   batch    = (const int*)d_in[4];
    const float* fc_w     = (const float*)d_in[5];
    const float* fc_b     = (const float*)d_in[6];
    const float* edge_emb = (const float*)d_in[7];
    const float* conv_w1  = (const float*)d_in[8];
    const float* conv_b1  = (const float*)d_in[9];
    const float* conv_bn_g= (const float*)d_in[10];
    const float* conv_bn_b= (const float*)d_in[11];
    const float* conv_w2  = (const float*)d_in[12];
    const float* conv_b2  = (const float*)d_in[13];
    const float* bn_g     = (const float*)d_in[14];
    const float* bn_b     = (const float*)d_in[15];
    const float* lstm_wih = (const float*)d_in[16];
    const float* lstm_bih = (const float*)d_in[18];
    const float* lstm_bhh = (const float*)d_in[19];
    const float* lin_w    = (const float*)d_in[20];
    const float* lin_b    = (const float*)d_in[21];
    float* out = (float*)d_out;

    const int* src = eidx;
    const int* dst = eidx + NEDGES;

    char* ws = (char*)d_ws;
    size_t o = 0;
    auto alloc = [&](size_t bytes) {
        size_t r = o;
        o += (bytes + 255) & ~(size_t)255;
        return r;
    };
    int*   deg    = (int*)(ws + alloc(NNODES * 4));
    int*   off    = (int*)(ws + alloc((NNODES + 1) * 4));
    int*   cursor = (int*)(ws + alloc(NNODES * 4));
    int*   pedge  = (int*)(ws + alloc(NEDGES * 4));
    int*   bsum   = (int*)(ws + alloc(256 * 4));
    int*   bpre   = (int*)(ws + alloc(256 * 4));
    float* h      = (float*)(ws + alloc((size_t)NNODES * HD * 4));
    _Float16* hf  = (_Float16*)(ws + alloc((size_t)NNODES * HD * 2));
    short* x0h    = (short*)(ws + alloc((size_t)NNODES * HD * 2));
    short* x0l    = (short*)(ws + alloc((size_t)NNODES * HD * 2));
    float* xmid   = (float*)(ws + alloc((size_t)NNODES * 2 * HD * 4));
    short* w1h    = (short*)(ws + alloc((size_t)NLAYER * 2 * HD * HD * 2));
    short* w1l    = (short*)(ws + alloc((size_t)NLAYER * 2 * HD * HD * 2));
    short* w2h    = (short*)(ws + alloc((size_t)NLAYER * 2 * HD * HD * 2));
    short* w2l    = (short*)(ws + alloc((size_t)NLAYER * 2 * HD * HD * 2));
    float* stats  = (float*)(ws + alloc(NLAYER * 768 * 4));

    // ---- CSR build + weight split ----
    hipMemsetAsync(deg, 0, NNODES * 4, stream);
    hipMemsetAsync(stats, 0, NLAYER * 768 * 4, stream);
    hist_kernel<<<(NEDGES + 255) / 256, 256, 0, stream>>>(dst, deg, NEDGES);
    blocksum_kernel<<<SCAN_BLOCKS, 256, 0, stream>>>(deg, bsum);
    scanpartials_kernel<<<1, 256, 0, stream>>>(bsum, bpre);
    writeoff_kernel<<<SCAN_BLOCKS, 256, 0, stream>>>(deg, bpre, off, cursor);
    scatter_kernel<<<(NEDGES + 255) / 256, 256, 0, stream>>>(src, dst, eattr, cursor, pedge, NEDGES);
    wsplit_kernel<<<(NLAYER * 2 * HD * HD + 255) / 256, 256, 0, stream>>>(
        conv_w1, conv_w2, w1h, w1l, w2h, w2l);

    // ---- input FC ----
    fc_kernel<<<(NNODES + 31) / 32, 256, 0, stream>>>(x, ncc, fc_w, fc_b, h, hf);

    const int gemmGridX = (NNODES + 255) / 256;
    for (int l = 0; l < NLAYER; ++l) {
        float* sumsA = stats + l * 768;
        float* sqsA  = sumsA + 256;
        float* sumsB = sumsA + 512;
        float* sqsB  = sumsA + 640;
        if (l == 0)
            agg_kernel<false><<<NNODES / 4, 256, 0, stream>>>(
                h, hf, off, pedge, edge_emb, nullptr, nullptr, nullptr, nullptr, x0h, x0l);
        else {
            float* pB = stats + (l - 1) * 768;
            agg_kernel<true><<<NNODES / 4, 256, 0, stream>>>(
                h, hf, off, pedge, edge_emb, pB + 512, pB + 640,
                bn_g + (l - 1) * HD, bn_b + (l - 1) * HD, x0h, x0l);
        }
        gemm_kernel<128, 4, 256, false><<<dim3(gemmGridX, 2), 512, 0, stream>>>(
            x0h, x0l, nullptr,
            w1h + (size_t)l * 2 * HD * HD, w1l + (size_t)l * 2 * HD * HD,
            conv_b1 + l * 2 * HD,
            nullptr, nullptr, nullptr, nullptr,
            xmid, nullptr, sumsA, sqsA, NNODES);
        gemm_kernel<64, 8, 128, true><<<dim3(gemmGridX, 2), 512, 0, stream>>>(
            nullptr, nullptr, xmid,
            w2h + (size_t)l * 2 * HD * HD, w2l + (size_t)l * 2 * HD * HD,
            conv_b2 + l * HD,
            sumsA, sqsA, conv_bn_g + l * 2 * HD, conv_bn_b + l * 2 * HD,
            h, hf, sumsB, sqsB, NNODES);
    }

    {
        float* pB = stats + (NLAYER - 1) * 768;
        pool_lstm_kernel<<<NGRAPH, 256, 0, stream>>>(
            h, batch, pB + 512, pB + 640,
            bn_g + (NLAYER - 1) * HD, bn_b + (NLAYER - 1) * HD,
            lstm_wih, lstm_bih, lstm_bhh, lin_w, lin_b, out);
    }
}

// Round 17
// 809.072 us; speedup vs baseline: 1.0950x; 1.0507x over previous
//
#include <hip/hip_runtime.h>
#include <hip/hip_bf16.h>
#include <hip/hip_fp16.h>
#include <math.h>

#define NNODES 50000
#define NEDGES 640000
#define NGRAPH 256
#define CIN 32
#define HD 128
#define NLAYER 5
#define LHID 64
#define COUT 10
#define EPS_GEN 1e-7f
#define INVN (1.f / (float)NNODES)
#define SCAN_BLOCKS 196

typedef __attribute__((ext_vector_type(8))) short short8;
typedef __attribute__((ext_vector_type(4))) float floatx4;
typedef __attribute__((ext_vector_type(4))) _Float16 half4v;

// truncating compensated split: v ~= bf(hi) + bf(lo)
__device__ __forceinline__ void fsplit(float v, short &hi, short &lo) {
    union { float f; unsigned u; } a; a.f = v;
    hi = (short)(a.u >> 16);
    union { unsigned u; float f; } b; b.u = a.u & 0xFFFF0000u;
    union { float f; unsigned u; } c; c.f = v - b.f;
    lo = (short)(c.u >> 16);
}

// ---------------- CSR build ----------------
__global__ void hist_kernel(const int* __restrict__ dst, int* __restrict__ deg, int e) {
    int i = blockIdx.x * blockDim.x + threadIdx.x;
    if (i < e) atomicAdd(&deg[dst[i]], 1);
}

__global__ void blocksum_kernel(const int* __restrict__ deg, int* __restrict__ bsum) {
    int i = blockIdx.x * 256 + threadIdx.x;
    int v = (i < NNODES) ? deg[i] : 0;
#pragma unroll
    for (int d = 32; d; d >>= 1) v += __shfl_down(v, d);
    __shared__ int ws4[4];
    if ((threadIdx.x & 63) == 0) ws4[threadIdx.x >> 6] = v;
    __syncthreads();
    if (threadIdx.x == 0) bsum[blockIdx.x] = ws4[0] + ws4[1] + ws4[2] + ws4[3];
}

__global__ void scanpartials_kernel(const int* __restrict__ bsum, int* __restrict__ bpre) {
    __shared__ int t[256];
    int i = threadIdx.x;
    t[i] = (i < SCAN_BLOCKS) ? bsum[i] : 0;
    __syncthreads();
    for (int d = 1; d < 256; d <<= 1) {
        int v = (i >= d) ? t[i - d] : 0;
        __syncthreads();
        t[i] += v;
        __syncthreads();
    }
    bpre[i] = (i == 0) ? 0 : t[i - 1];
}

__global__ void writeoff_kernel(const int* __restrict__ deg, const int* __restrict__ bpre,
                                int* __restrict__ off, int* __restrict__ cursor) {
    __shared__ int t[256];
    int tid = threadIdx.x;
    int i = blockIdx.x * 256 + tid;
    int v = (i < NNODES) ? deg[i] : 0;
    t[tid] = v;
    __syncthreads();
    for (int d = 1; d < 256; d <<= 1) {
        int u = (tid >= d) ? t[tid - d] : 0;
        __syncthreads();
        t[tid] += u;
        __syncthreads();
    }
    int excl = bpre[blockIdx.x] + t[tid] - v;
    if (i < NNODES) { off[i] = excl; cursor[i] = excl; }
    if (i == NNODES - 1) off[NNODES] = excl + v;
}

__global__ void scatter_kernel(const int* __restrict__ src, const int* __restrict__ dst,
                               const int* __restrict__ eattr, int* __restrict__ cursor,
                               int* __restrict__ pedge, int e) {
    int i = blockIdx.x * blockDim.x + threadIdx.x;
    if (i < e) {
        int slot = atomicAdd(&cursor[dst[i]], 1);
        pedge[slot] = src[i] | (eattr[i] << 27);
    }
}

// ---------------- weight split (once per launch) ----------------
__global__ void wsplit_kernel(const float* __restrict__ w1, const float* __restrict__ w2,
                              short* __restrict__ w1h, short* __restrict__ w1l,
                              short* __restrict__ w2h, short* __restrict__ w2l) {
    int i = blockIdx.x * 256 + threadIdx.x;
    if (i < NLAYER * 2 * HD * HD) {
        short hi, lo;
        fsplit(w1[i], hi, lo);
        w1h[i] = hi; w1l[i] = lo;
        fsplit(w2[i], hi, lo);
        w2h[i] = hi; w2l[i] = lo;
    }
}

// ---------------- input FC: weights in VGPRs, broadcast x loads ----------------
__global__ __launch_bounds__(256) void fc_kernel(
    const float* __restrict__ x, const float* __restrict__ ncc,
    const float* __restrict__ w, const float* __restrict__ b,
    float* __restrict__ h, _Float16* __restrict__ hf) {
    __shared__ float ws[HD][41];
    int tid = threadIdx.x;
    for (int i = tid; i < HD * 40; i += 256) ws[i / 40][i % 40] = w[i];
    __syncthreads();
    int c = tid & 127;
    int half = tid >> 7;
    float wreg[40];
#pragma unroll
    for (int k = 0; k < 40; ++k) wreg[k] = ws[c][k];
    float bc = b[c];
    bool full = (blockIdx.x + 1) * 32 <= NNODES;
    if (full) {
#pragma unroll
        for (int nn = 0; nn < 16; ++nn) {
            int node = blockIdx.x * 32 + nn * 2 + half;
            const float4* xr = reinterpret_cast<const float4*>(x + (size_t)node * CIN);
            const float4* nr = reinterpret_cast<const float4*>(ncc + (size_t)node * 8);
            float acc = bc;
#pragma unroll
            for (int k4 = 0; k4 < 8; ++k4) {
                float4 xv = xr[k4];
                acc = fmaf(xv.x, wreg[k4 * 4 + 0], acc);
                acc = fmaf(xv.y, wreg[k4 * 4 + 1], acc);
                acc = fmaf(xv.z, wreg[k4 * 4 + 2], acc);
                acc = fmaf(xv.w, wreg[k4 * 4 + 3], acc);
            }
#pragma unroll
            for (int k4 = 0; k4 < 2; ++k4) {
                float4 nv = nr[k4];
                acc = fmaf(nv.x, wreg[32 + k4 * 4 + 0], acc);
                acc = fmaf(nv.y, wreg[32 + k4 * 4 + 1], acc);
                acc = fmaf(nv.z, wreg[32 + k4 * 4 + 2], acc);
                acc = fmaf(nv.w, wreg[32 + k4 * 4 + 3], acc);
            }
            h[(size_t)node * HD + c] = acc;
            hf[(size_t)node * HD + c] = (_Float16)acc;
        }
    } else {
        for (int nn = 0; nn < 16; ++nn) {
            int node = blockIdx.x * 32 + nn * 2 + half;
            if (node >= NNODES) break;
            const float4* xr = reinterpret_cast<const float4*>(x + (size_t)node * CIN);
            const float4* nr = reinterpret_cast<const float4*>(ncc + (size_t)node * 8);
            float acc = bc;
            for (int k4 = 0; k4 < 8; ++k4) {
                float4 xv = xr[k4];
                acc = fmaf(xv.x, wreg[k4 * 4 + 0], acc);
                acc = fmaf(xv.y, wreg[k4 * 4 + 1], acc);
                acc = fmaf(xv.z, wreg[k4 * 4 + 2], acc);
                acc = fmaf(xv.w, wreg[k4 * 4 + 3], acc);
            }
            for (int k4 = 0; k4 < 2; ++k4) {
                float4 nv = nr[k4];
                acc = fmaf(nv.x, wreg[32 + k4 * 4 + 0], acc);
                acc = fmaf(nv.y, wreg[32 + k4 * 4 + 1], acc);
                acc = fmaf(nv.z, wreg[32 + k4 * 4 + 2], acc);
                acc = fmaf(nv.w, wreg[32 + k4 * 4 + 3], acc);
            }
            h[(size_t)node * HD + c] = acc;
            hf[(size_t)node * HD + c] = (_Float16)acc;
        }
    }
}

// ---------------- softmax aggregation: fp16 gather, fp32 residual ----------------
template <bool BN>
__global__ __launch_bounds__(256) void agg_kernel(
    const float* __restrict__ h, const _Float16* __restrict__ hf,
    const int* __restrict__ off,
    const int* __restrict__ pedge, const float* __restrict__ edge_emb,
    const float* __restrict__ sums, const float* __restrict__ sqs,
    const float* __restrict__ g, const float* __restrict__ bb,
    short* __restrict__ x0h, short* __restrict__ x0l) {
    __shared__ float ee[4 * HD];
    __shared__ float scs[HD], shs[HD];
    int tid = threadIdx.x;
    ee[tid] = edge_emb[tid];
    ee[tid + 256] = edge_emb[tid + 256];
    if (BN && tid < HD) {
        float mu = sums[tid] * INVN;
        float var = fmaxf(sqs[tid] * INVN - mu * mu, 0.f);
        float is = rsqrtf(var + 1e-5f);
        float sc = g[tid] * is;
        scs[tid] = sc;
        shs[tid] = bb[tid] - mu * sc;
    }
    __syncthreads();

    int node = blockIdx.x * 4 + (tid >> 6);
    int lane = tid & 63;
    int half = lane >> 5;
    int c4 = (lane & 31) * 4;

    int b = off[node], e = off[node + 1];
    float4 sc4 = make_float4(1.f, 1.f, 1.f, 1.f);
    float4 sh4 = make_float4(0.f, 0.f, 0.f, 0.f);
    if (BN) {
        sc4 = *reinterpret_cast<const float4*>(&scs[c4]);
        sh4 = *reinterpret_cast<const float4*>(&shs[c4]);
    }
    float4 S = make_float4(0.f, 0.f, 0.f, 0.f);
    float4 T = make_float4(0.f, 0.f, 0.f, 0.f);
    int j = b + half;
    unsigned pnext = (j < e) ? (unsigned)pedge[j] : 0u;
    for (; j < e; j += 2) {
        unsigned p = pnext;
        if (j + 2 < e) pnext = (unsigned)pedge[j + 2];
        int s = p & 0x07FFFFFFu;
        int a = p >> 27;
        half4v uv = *reinterpret_cast<const half4v*>(&hf[(size_t)s * HD + c4]);
        float4 ev = *reinterpret_cast<const float4*>(&ee[a * HD + c4]);
        float4 v = make_float4((float)uv.x, (float)uv.y, (float)uv.z, (float)uv.w);
        if (BN) {
            v.x = fmaxf(fmaf(v.x, sc4.x, sh4.x), 0.f);
            v.y = fmaxf(fmaf(v.y, sc4.y, sh4.y), 0.f);
            v.z = fmaxf(fmaf(v.z, sc4.z, sh4.z), 0.f);
            v.w = fmaxf(fmaf(v.w, sc4.w, sh4.w), 0.f);
        }
        float m0 = fmaxf(v.x + ev.x, 0.f) + EPS_GEN;
        float m1 = fmaxf(v.y + ev.y, 0.f) + EPS_GEN;
        float m2 = fmaxf(v.z + ev.z, 0.f) + EPS_GEN;
        float m3 = fmaxf(v.w + ev.w, 0.f) + EPS_GEN;
        float e0 = __expf(m0), e1 = __expf(m1), e2 = __expf(m2), e3 = __expf(m3);
        S.x += e0; S.y += e1; S.z += e2; S.w += e3;
        T.x = fmaf(e0, m0, T.x); T.y = fmaf(e1, m1, T.y);
        T.z = fmaf(e2, m2, T.z); T.w = fmaf(e3, m3, T.w);
    }
    S.x += __shfl(S.x, lane ^ 32); S.y += __shfl(S.y, lane ^ 32);
    S.z += __shfl(S.z, lane ^ 32); S.w += __shfl(S.w, lane ^ 32);
    T.x += __shfl(T.x, lane ^ 32); T.y += __shfl(T.y, lane ^ 32);
    T.z += __shfl(T.z, lane ^ 32); T.w += __shfl(T.w, lane ^ 32);
    if (half == 0) {
        float4 r = *reinterpret_cast<const float4*>(&h[(size_t)node * HD + c4]);
        if (BN) {
            r.x = fmaxf(fmaf(r.x, sc4.x, sh4.x), 0.f);
            r.y = fmaxf(fmaf(r.y, sc4.y, sh4.y), 0.f);
            r.z = fmaxf(fmaf(r.z, sc4.z, sh4.z), 0.f);
            r.w = fmaxf(fmaf(r.w, sc4.w, sh4.w), 0.f);
        }
        if (e > b) {
            r.x += T.x / S.x; r.y += T.y / S.y;
            r.z += T.z / S.z; r.w += T.w / S.w;
        }
        float vv[4] = {r.x, r.y, r.z, r.w};
        short4 hv, lv;
        short hh4[4], ll4[4];
#pragma unroll
        for (int q = 0; q < 4; ++q) fsplit(vv[q], hh4[q], ll4[q]);
        hv.x = hh4[0]; hv.y = hh4[1]; hv.z = hh4[2]; hv.w = hh4[3];
        lv.x = ll4[0]; lv.y = ll4[1]; lv.z = ll4[2]; lv.w = ll4[3];
        *reinterpret_cast<short4*>(&x0h[(size_t)node * HD + c4]) = hv;
        *reinterpret_cast<short4*>(&x0l[(size_t)node * HD + c4]) = lv;
    }
}

// ---------------- MFMA GEMM: B-stationary LDS, barrier-free compute, 512 thr / BM=256 ----------------
// TRANS path: raw-load issue decoupled from BN-fold/split so the compiler can
// wait with fine-grained vmcnt (loads of kt+1 stay in flight across kt's MFMAs).
template <int NPANEL, int KT, int NFULL, bool TRANS>
__global__ __launch_bounds__(512) void gemm_kernel(
    const short* __restrict__ Ahg, const short* __restrict__ Alg,
    const float* __restrict__ Afp,
    const short* __restrict__ Bhg, const short* __restrict__ Blg,
    const float* __restrict__ bias,
    const float* __restrict__ sums_in, const float* __restrict__ sqs_in,
    const float* __restrict__ g_in, const float* __restrict__ b_in,
    float* __restrict__ C, _Float16* __restrict__ Chf,
    float* __restrict__ sums, float* __restrict__ sqs,
    int M) {
    constexpr int K = KT * 32;
    constexpr int BSTRIDE = K + 8;
    constexpr int NT = NPANEL / 16;
    __shared__ short Bs[2][NPANEL][BSTRIDE];
    __shared__ float scol[NPANEL], sqcol[NPANEL];
    __shared__ float sL[256], shL[256];
    int tid = threadIdx.x;
    int m0 = blockIdx.x * 256;
    int n0 = blockIdx.y * NPANEL;
    if (tid < NPANEL) { scol[tid] = 0.f; sqcol[tid] = 0.f; }
    if (TRANS && tid < K) {
        float mu = sums_in[tid] * INVN;
        float var = fmaxf(sqs_in[tid] * INVN - mu * mu, 0.f);
        float is = rsqrtf(var + 1e-5f);
        float sc = g_in[tid] * is;
        sL[tid] = sc;
        shL[tid] = b_in[tid] - mu * sc;
    }
    constexpr int ELEMS = NPANEL * (K / 8);
#pragma unroll
    for (int i = tid; i < ELEMS; i += 512) {
        int n = i / (K / 8);
        int k8 = (i % (K / 8)) * 8;
        *reinterpret_cast<short8*>(&Bs[0][n][k8]) =
            *reinterpret_cast<const short8*>(&Bhg[(size_t)(n0 + n) * K + k8]);
        *reinterpret_cast<short8*>(&Bs[1][n][k8]) =
            *reinterpret_cast<const short8*>(&Blg[(size_t)(n0 + n) * K + k8]);
    }
    __syncthreads();

    int wv = tid >> 6;
    int lane = tid & 63;
    int ml = lane & 15;
    int quad = lane >> 4;
    int mrow0 = m0 + wv * 32;

    floatx4 acc[2][NT];
#pragma unroll
    for (int mt = 0; mt < 2; ++mt)
#pragma unroll
        for (int nt = 0; nt < NT; ++nt) acc[mt][nt] = (floatx4){0.f, 0.f, 0.f, 0.f};

    int arow[2];
#pragma unroll
    for (int mt = 0; mt < 2; ++mt) arow[mt] = min(mrow0 + mt * 16 + ml, M - 1);

    if (!TRANS) {
        short8 ah[2][KT], al[2][KT];
#pragma unroll
        for (int mt = 0; mt < 2; ++mt)
#pragma unroll
            for (int kt = 0; kt < KT; ++kt) {
                size_t aoff = (size_t)arow[mt] * K + kt * 32 + quad * 8;
                ah[mt][kt] = *reinterpret_cast<const short8*>(&Ahg[aoff]);
                al[mt][kt] = *reinterpret_cast<const short8*>(&Alg[aoff]);
            }
#pragma unroll
        for (int kt = 0; kt < KT; ++kt)
#pragma unroll
            for (int nt = 0; nt < NT; ++nt) {
                short8 bh = *reinterpret_cast<const short8*>(&Bs[0][nt * 16 + ml][kt * 32 + quad * 8]);
                short8 bl = *reinterpret_cast<const short8*>(&Bs[1][nt * 16 + ml][kt * 32 + quad * 8]);
#pragma unroll
                for (int mt = 0; mt < 2; ++mt) {
                    acc[mt][nt] = __builtin_amdgcn_mfma_f32_16x16x32_bf16(ah[mt][kt], bh, acc[mt][nt], 0, 0, 0);
                    acc[mt][nt] = __builtin_amdgcn_mfma_f32_16x16x32_bf16(al[mt][kt], bh, acc[mt][nt], 0, 0, 0);
                    acc[mt][nt] = __builtin_amdgcn_mfma_f32_16x16x32_bf16(ah[mt][kt], bl, acc[mt][nt], 0, 0, 0);
                }
            }
    } else {
        float4 raw[2][2][2];   // [buf][mt][lo/hi half of 8 floats]
        auto issue = [&](int kt, int buf) {
#pragma unroll
            for (int mt = 0; mt < 2; ++mt) {
                const float* ap = &Afp[(size_t)arow[mt] * K + kt * 32 + quad * 8];
                raw[buf][mt][0] = *reinterpret_cast<const float4*>(ap);
                raw[buf][mt][1] = *reinterpret_cast<const float4*>(ap + 4);
            }
        };
        issue(0, 0);
        for (int kt = 0; kt < KT; ++kt) {
            int cur = kt & 1;
            if (kt + 1 < KT) issue(kt + 1, cur ^ 1);
            // process current (waits only on raw[cur]; raw[cur^1] stays in flight)
            short8 ah[2], al[2];
            int kg = kt * 32 + quad * 8;
            float4 s0 = *reinterpret_cast<const float4*>(&sL[kg]);
            float4 s1 = *reinterpret_cast<const float4*>(&sL[kg + 4]);
            float4 h0 = *reinterpret_cast<const float4*>(&shL[kg]);
            float4 h1 = *reinterpret_cast<const float4*>(&shL[kg + 4]);
#pragma unroll
            for (int mt = 0; mt < 2; ++mt) {
                float4 v0 = raw[cur][mt][0];
                float4 v1 = raw[cur][mt][1];
                float vv[8] = {
                    fmaxf(fmaf(v0.x, s0.x, h0.x), 0.f), fmaxf(fmaf(v0.y, s0.y, h0.y), 0.f),
                    fmaxf(fmaf(v0.z, s0.z, h0.z), 0.f), fmaxf(fmaf(v0.w, s0.w, h0.w), 0.f),
                    fmaxf(fmaf(v1.x, s1.x, h1.x), 0.f), fmaxf(fmaf(v1.y, s1.y, h1.y), 0.f),
                    fmaxf(fmaf(v1.z, s1.z, h1.z), 0.f), fmaxf(fmaf(v1.w, s1.w, h1.w), 0.f)};
                short8 hv, lv;
#pragma unroll
                for (int q = 0; q < 8; ++q) {
                    short hb, lb;
                    fsplit(vv[q], hb, lb);
                    hv[q] = hb;
                    lv[q] = lb;
                }
                ah[mt] = hv;
                al[mt] = lv;
            }
#pragma unroll
            for (int nt = 0; nt < NT; ++nt) {
                short8 bh = *reinterpret_cast<const short8*>(&Bs[0][nt * 16 + ml][kt * 32 + quad * 8]);
                short8 bl = *reinterpret_cast<const short8*>(&Bs[1][nt * 16 + ml][kt * 32 + quad * 8]);
#pragma unroll
                for (int mt = 0; mt < 2; ++mt) {
                    acc[mt][nt] = __builtin_amdgcn_mfma_f32_16x16x32_bf16(ah[mt], bh, acc[mt][nt], 0, 0, 0);
                    acc[mt][nt] = __builtin_amdgcn_mfma_f32_16x16x32_bf16(al[mt], bh, acc[mt][nt], 0, 0, 0);
                    acc[mt][nt] = __builtin_amdgcn_mfma_f32_16x16x32_bf16(ah[mt], bl, acc[mt][nt], 0, 0, 0);
                }
            }
        }
    }

    // epilogue: bias + store (+ fp16 mirror for GEMM2); stats via quad shfl-reduce
#pragma unroll
    for (int nt = 0; nt < NT; ++nt) {
        int col = nt * 16 + ml;
        float bv = bias[n0 + col];
        float cs = 0.f, cq = 0.f;
#pragma unroll
        for (int mt = 0; mt < 2; ++mt)
#pragma unroll
            for (int r = 0; r < 4; ++r) {
                int m = mrow0 + mt * 16 + quad * 4 + r;
                if (m < M) {
                    float v = acc[mt][nt][r] + bv;
                    C[(size_t)m * NFULL + n0 + col] = v;
                    if (Chf) Chf[(size_t)m * NFULL + n0 + col] = (_Float16)v;
                    cs += v; cq += v * v;
                }
            }
        cs += __shfl(cs, lane ^ 16); cq += __shfl(cq, lane ^ 16);
        cs += __shfl(cs, lane ^ 32); cq += __shfl(cq, lane ^ 32);
        if (quad == 0) {
            atomicAdd(&scol[col], cs);
            atomicAdd(&sqcol[col], cq);
        }
    }
    __syncthreads();
    if (tid < NPANEL) {
        atomicAdd(&sums[n0 + tid], scol[tid]);
        atomicAdd(&sqs[n0 + tid], sqcol[tid]);
    }
}

// ---------------- fused pool (BN+ReLU folded) + LSTM + linear ----------------
__global__ __launch_bounds__(256) void pool_lstm_kernel(
    const float* __restrict__ h, const int* __restrict__ batch,
    const float* __restrict__ sums, const float* __restrict__ sqs,
    const float* __restrict__ g, const float* __restrict__ bb,
    const float* __restrict__ wih, const float* __restrict__ bih,
    const float* __restrict__ bhh, const float* __restrict__ lin_w,
    const float* __restrict__ lin_b, float* __restrict__ out) {
    __shared__ int range[2];
    __shared__ float acc2[256];
    __shared__ float pr[HD];
    __shared__ float gates[4 * LHID];
    __shared__ float hh[LHID];
    int gid = blockIdx.x;
    int tid = threadIdx.x;
    if (tid < 2) {
        int target = gid + tid;
        int lo = 0, hi = NNODES;
        while (lo < hi) {
            int mid = (lo + hi) >> 1;
            if (batch[mid] < target) lo = mid + 1; else hi = mid;
        }
        range[tid] = lo;
    }
    __syncthreads();
    int s0 = range[0], s1 = range[1];
    int c = tid & 127;
    int half = tid >> 7;
    float mu = sums[c] * INVN;
    float var = fmaxf(sqs[c] * INVN - mu * mu, 0.f);
    float is = rsqrtf(var + 1e-5f);
    float sc = g[c] * is;
    float sh = bb[c] - mu * sc;
    float a = 0.f;
    for (int r = s0 + half; r < s1; r += 2)
        a += fmaxf(fmaf(h[(size_t)r * HD + c], sc, sh), 0.f);
    acc2[tid] = a;
    __syncthreads();
    if (half == 0) pr[c] = acc2[c] + acc2[c + 128];
    __syncthreads();
    {
        float acc = bih[tid] + bhh[tid];
        const float* wr = wih + tid * HD;
        for (int k = 0; k < HD; ++k) acc += pr[k] * wr[k];
        gates[tid] = acc;
    }
    __syncthreads();
    if (tid < LHID) {
        float ig = gates[tid];
        float gg = gates[2 * LHID + tid];
        float og = gates[3 * LHID + tid];
        float cc = (1.f / (1.f + __expf(-ig))) * tanhf(gg);
        hh[tid] = (1.f / (1.f + __expf(-og))) * tanhf(cc);
    }
    __syncthreads();
    if (tid < COUT) {
        float acc = lin_b[tid];
        const float* lr = lin_w + tid * LHID;
        for (int k = 0; k < LHID; ++k) acc += hh[k] * lr[k];
        out[gid * COUT + tid] = acc;
    }
}

extern "C" void kernel_launch(void* const* d_in, const int* in_sizes, int n_in,
                              void* d_out, int out_size, void* d_ws, size_t ws_size,
                              hipStream_t stream) {
    const float* x        = (const float*)d_in[0];
    const float* ncc      = (const float*)d_in[1];
    const int*   eidx     = (const int*)d_in[2];
    const int*   eattr    = (const int*)d_in[3];
    const int*   batch    = (const int*)d_in[4];
    const float* fc_w     = (const float*)d_in[5];
    const float* fc_b     = (const float*)d_in[6];
    const float* edge_emb = (const float*)d_in[7];
    const float* conv_w1  = (const float*)d_in[8];
    const float* conv_b1  = (const float*)d_in[9];
    const float* conv_bn_g= (const float*)d_in[10];
    const float* conv_bn_b= (const float*)d_in[11];
    const float* conv_w2  = (const float*)d_in[12];
    const float* conv_b2  = (const float*)d_in[13];
    const float* bn_g     = (const float*)d_in[14];
    const float* bn_b     = (const float*)d_in[15];
    const float* lstm_wih = (const float*)d_in[16];
    const float* lstm_bih = (const float*)d_in[18];
    const float* lstm_bhh = (const float*)d_in[19];
    const float* lin_w    = (const float*)d_in[20];
    const float* lin_b    = (const float*)d_in[21];
    float* out = (float*)d_out;

    const int* src = eidx;
    const int* dst = eidx + NEDGES;

    char* ws = (char*)d_ws;
    size_t o = 0;
    auto alloc = [&](size_t bytes) {
        size_t r = o;
        o += (bytes + 255) & ~(size_t)255;
        return r;
    };
    int*   deg    = (int*)(ws + alloc(NNODES * 4));
    int*   off    = (int*)(ws + alloc((NNODES + 1) * 4));
    int*   cursor = (int*)(ws + alloc(NNODES * 4));
    int*   pedge  = (int*)(ws + alloc(NEDGES * 4));
    int*   bsum   = (int*)(ws + alloc(256 * 4));
    int*   bpre   = (int*)(ws + alloc(256 * 4));
    float* h      = (float*)(ws + alloc((size_t)NNODES * HD * 4));
    _Float16* hf  = (_Float16*)(ws + alloc((size_t)NNODES * HD * 2));
    short* x0h    = (short*)(ws + alloc((size_t)NNODES * HD * 2));
    short* x0l    = (short*)(ws + alloc((size_t)NNODES * HD * 2));
    float* xmid   = (float*)(ws + alloc((size_t)NNODES * 2 * HD * 4));
    short* w1h    = (short*)(ws + alloc((size_t)NLAYER * 2 * HD * HD * 2));
    short* w1l    = (short*)(ws + alloc((size_t)NLAYER * 2 * HD * HD * 2));
    short* w2h    = (short*)(ws + alloc((size_t)NLAYER * 2 * HD * HD * 2));
    short* w2l    = (short*)(ws + alloc((size_t)NLAYER * 2 * HD * HD * 2));
    float* stats  = (float*)(ws + alloc(NLAYER * 768 * 4));

    // ---- CSR build + weight split ----
    hipMemsetAsync(deg, 0, NNODES * 4, stream);
    hipMemsetAsync(stats, 0, NLAYER * 768 * 4, stream);
    hist_kernel<<<(NEDGES + 255) / 256, 256, 0, stream>>>(dst, deg, NEDGES);
    blocksum_kernel<<<SCAN_BLOCKS, 256, 0, stream>>>(deg, bsum);
    scanpartials_kernel<<<1, 256, 0, stream>>>(bsum, bpre);
    writeoff_kernel<<<SCAN_BLOCKS, 256, 0, stream>>>(deg, bpre, off, cursor);
    scatter_kernel<<<(NEDGES + 255) / 256, 256, 0, stream>>>(src, dst, eattr, cursor, pedge, NEDGES);
    wsplit_kernel<<<(NLAYER * 2 * HD * HD + 255) / 256, 256, 0, stream>>>(
        conv_w1, conv_w2, w1h, w1l, w2h, w2l);

    // ---- input FC ----
    fc_kernel<<<(NNODES + 31) / 32, 256, 0, stream>>>(x, ncc, fc_w, fc_b, h, hf);

    const int gemmGridX = (NNODES + 255) / 256;
    for (int l = 0; l < NLAYER; ++l) {
        float* sumsA = stats + l * 768;
        float* sqsA  = sumsA + 256;
        float* sumsB = sumsA + 512;
        float* sqsB  = sumsA + 640;
        if (l == 0)
            agg_kernel<false><<<NNODES / 4, 256, 0, stream>>>(
                h, hf, off, pedge, edge_emb, nullptr, nullptr, nullptr, nullptr, x0h, x0l);
        else {
            float* pB = stats + (l - 1) * 768;
            agg_kernel<true><<<NNODES / 4, 256, 0, stream>>>(
                h, hf, off, pedge, edge_emb, pB + 512, pB + 640,
                bn_g + (l - 1) * HD, bn_b + (l - 1) * HD, x0h, x0l);
        }
        gemm_kernel<128, 4, 256, false><<<dim3(gemmGridX, 2), 512, 0, stream>>>(
            x0h, x0l, nullptr,
            w1h + (size_t)l * 2 * HD * HD, w1l + (size_t)l * 2 * HD * HD,
            conv_b1 + l * 2 * HD,
            nullptr, nullptr, nullptr, nullptr,
            xmid, nullptr, sumsA, sqsA, NNODES);
        gemm_kernel<64, 8, 128, true><<<dim3(gemmGridX, 2), 512, 0, stream>>>(
            nullptr, nullptr, xmid,
            w2h + (size_t)l * 2 * HD * HD, w2l + (size_t)l * 2 * HD * HD,
            conv_b2 + l * HD,
            sumsA, sqsA, conv_bn_g + l * 2 * HD, conv_bn_b + l * 2 * HD,
            h, hf, sumsB, sqsB, NNODES);
    }

    {
        float* pB = stats + (NLAYER - 1) * 768;
        pool_lstm_kernel<<<NGRAPH, 256, 0, stream>>>(
            h, batch, pB + 512, pB + 640,
            bn_g + (NLAYER - 1) * HD, bn_b + (NLAYER - 1) * HD,
            lstm_wih, lstm_bih, lstm_bhh, lin_w, lin_b, out);
    }
}